// Round 6
// baseline (1195.642 us; speedup 1.0000x reference)
//
#include <hip/hip_runtime.h>
#include <hip/hip_bf16.h>

#define DD 80
#define CIN 32
#define PLANE (DD*DD)        // 6400
#define VOX (DD*DD*DD)       // 512000
#define NPTS 200000

typedef __attribute__((ext_vector_type(8))) short bf16x8;
typedef __attribute__((ext_vector_type(4))) float floatx4;

static __device__ __forceinline__ short f2bf(float v) {
    __hip_bfloat16 b = __float2bfloat16(v);
    return *(short*)&b;
}

// async global->LDS 16B copy: lane's 16B lands at ldsbase + lane*16 (wave-uniform base);
// the GLOBAL source address is per-lane.
static __device__ __forceinline__ void async_copy16(void* lds, const void* g) {
    __builtin_amdgcn_global_load_lds(
        (const __attribute__((address_space(1))) unsigned int*)g,
        (__attribute__((address_space(3))) unsigned int*)lds, 16, 0, 0);
}

// ---------------- K0: convert/permute all weights to bf16 ----------------
// wpb NOW holds conv2 B in exact MFMA-fragment order: [off][nt][ks][lane][e]
// (lane = q*16+lc -> oc = nt*16+lc, ic = ks*32+q*8+e). One wave load of
// wpb + off*4096 + nt*1024 + ks*512 + lane*8 is a dense, coalesced 1 KB fragment.
__global__ void convert_weights(const float* __restrict__ w2,
                                const float* __restrict__ w_p1,
                                const float* __restrict__ w_p2,
                                const float* __restrict__ w_p3,
                                const float* __restrict__ w_e1,
                                short* __restrict__ wpb, short* __restrict__ w1b,
                                short* __restrict__ w2b, short* __restrict__ w3b,
                                short* __restrict__ wc1) {
    int i = blockIdx.x * 256 + threadIdx.x;      // total 264192
    if (i < 110592) {
        int off = i >> 12, r = i & 4095;
        int nt = r >> 10, r2 = r & 1023;
        int ks = r2 >> 9, r3 = r2 & 511;
        int lane = r3 >> 3, e = r3 & 7;
        int oc = nt * 16 + (lane & 15);
        int ic = ks * 32 + (lane >> 4) * 8 + e;
        wpb[i] = f2bf(w2[oc * 1728 + ic * 27 + off]);
    } else if (i < 110592 + 16384) {
        int j = i - 110592;
        w1b[j] = f2bf(w_p1[j]);
    } else if (i < 110592 + 16384 + 65536) {
        int j = i - 110592 - 16384;
        w2b[j] = f2bf(w_p2[j]);
    } else if (i < 110592 + 16384 + 65536 + 16384) {
        int j = i - 110592 - 16384 - 65536;
        w3b[j] = f2bf(w_p3[j]);
    } else if (i < 110592 + 16384 + 65536 + 16384 + 55296) {
        int j = i - (110592 + 16384 + 65536 + 16384);   // [off][oc][ic]
        int off = j / 2048, r = j - off * 2048;
        int oc = r >> 5, ic = r & 31;
        wc1[j] = f2bf(w_e1[(oc * 32 + ic) * 27 + off]);
    }
}

// ---------------- K0b: transpose img (32,VOX) fp32 -> img_t [vox][32] bf16 ----------------
__global__ __launch_bounds__(256) void transpose_img(
    const float* __restrict__ img, short* __restrict__ img_t)
{
    int v = blockIdx.x * 256 + threadIdx.x;
    if (v >= VOX) return;
    short row[32];
    #pragma unroll
    for (int ic = 0; ic < 32; ic++)
        row[ic] = f2bf(img[(size_t)ic * VOX + v]);
    int4* dst = (int4*)(img_t + (size_t)v * 32);
    #pragma unroll
    for (int c = 0; c < 4; c++) dst[c] = ((int4*)row)[c];
}

// ---------------- K1: conv1 via implicit-GEMM MFMA, async LDS staging ----------------
__global__ __launch_bounds__(256) void conv1_mfma(
    const short* __restrict__ img_t, const short* __restrict__ wc1,
    const float* __restrict__ b1, const short* __restrict__ zeros,
    short* __restrict__ f1)
{
    __shared__ short Alds[3072 * 16 / 2];   // 48 KB

    const int bh = blockIdx.x;
    const int d = bh / DD, h = bh - d * DD;
    const int tid = threadIdx.x;
    const int w = tid >> 6, lane = tid & 63;
    const int q = lane >> 4, lc = lane & 15;

    for (int i = 0; i < 12; i++) {
        int s = (w * 12 + i) * 64 + lane;      // slot 0..3071
        int row = s >> 2, c = s & 3;
        int cs = c ^ (row & 3);                // swizzled source chunk
        int rr = row / 82, v = row - rr * 82;
        int dz = rr / 3, dyy = rr - dz * 3;
        int zz = d + dz - 1, yy = h + dyy - 1, ww = v - 1;
        const short* src = zeros;
        if (row < 738 && (unsigned)zz < DD && (unsigned)yy < DD && (unsigned)ww < DD)
            src = img_t + ((size_t)(zz * PLANE + yy * DD + ww)) * 32 + cs * 8;
        async_copy16(&Alds[(w * 12 + i) * 512], src);
    }
    __syncthreads();

    floatx4 acc[5];
    #pragma unroll
    for (int mt = 0; mt < 5; mt++) acc[mt] = (floatx4){0.f, 0.f, 0.f, 0.f};

    #pragma unroll 3
    for (int off = 0; off < 27; ++off) {
        const int dz = off / 9, rem = off - dz * 9;
        const int dy = rem / 3, dx = rem - dy * 3;
        const int rr = dz * 3 + dy;
        bf16x8 bfr = *(const bf16x8*)(wc1 + ((off * 64 + w * 16 + lc) << 5) + q * 8);
        #pragma unroll
        for (int mt = 0; mt < 5; mt++) {
            const int vv = rr * 82 + mt * 16 + lc + dx;
            bf16x8 afr = *(const bf16x8*)(&Alds[vv * 32 + ((q ^ (vv & 3)) << 3)]);
            acc[mt] = __builtin_amdgcn_mfma_f32_16x16x32_bf16(afr, bfr, acc[mt], 0, 0, 0);
        }
    }

    const int oc = w * 16 + lc;
    const float bias = b1[oc];
    const size_t vbase = (size_t)(d * DD + h) * DD;
    #pragma unroll
    for (int mt = 0; mt < 5; mt++) {
        #pragma unroll
        for (int r = 0; r < 4; r++) {
            const int m = mt * 16 + q * 4 + r;
            float v = acc[mt][r] + bias;
            f1[(vbase + m) * 64 + oc] = f2bf(v > 0.f ? v : 0.f);
        }
    }
}

// ---------------- binning v2: LDS-histogram counting sort (ZERO global atomics) ----------------
// Round-5's global-atomic sort cost ~85 us (200K same-line atomics ping-pong across 8 XCD L2s).
// v2: 64 blocks build per-block LDS histograms (LDS atomics only), one scan block computes
// cell starts + per-(block,cell) bases, scatter ranks via LDS atomics and writes directly.
#define NSB 64   // sort blocks

__global__ __launch_bounds__(512) void hist_cells(
    const int* __restrict__ c0, const int* __restrict__ c1, const int* __restrict__ c2,
    int* __restrict__ partial)
{
    __shared__ int h[1000];
    const int tid = threadIdx.x;
    for (int c = tid; c < 1000; c += 512) h[c] = 0;
    __syncthreads();
    for (int p = blockIdx.x * 512 + tid; p < NPTS; p += NSB * 512) {
        int cell = (c0[p] >> 3) * 100 + (c1[p] >> 3) * 10 + (c2[p] >> 3);
        atomicAdd(&h[cell], 1);
    }
    __syncthreads();
    for (int c = tid; c < 1000; c += 512) partial[blockIdx.x * 1000 + c] = h[c];
}

__global__ __launch_bounds__(1024) void scan_cells(
    const int* __restrict__ partial, int* __restrict__ blockbase,
    int* __restrict__ cs, int* __restrict__ ce)
{
    __shared__ int a[1024], b[1024];
    const int t = threadIdx.x;
    int sum = 0;
    if (t < 1000) {
        for (int bb = 0; bb < NSB; bb++) {
            blockbase[bb * 1000 + t] = sum;          // within-cell prefix over blocks
            sum += partial[bb * 1000 + t];
        }
    }
    a[t] = sum;
    __syncthreads();
    int* src = a; int* dst = b;
    for (int d = 1; d < 1024; d <<= 1) {
        int v = src[t];
        if (t >= d) v += src[t - d];
        dst[t] = v;
        __syncthreads();
        int* tmp = src; src = dst; dst = tmp;
    }
    if (t < 1000) { cs[t] = src[t] - sum; ce[t] = src[t]; }
}

__global__ __launch_bounds__(512) void scatter_points(
    const int* __restrict__ c0, const int* __restrict__ c1, const int* __restrict__ c2,
    const int* __restrict__ cs, const int* __restrict__ blockbase,
    int* __restrict__ perm, int* __restrict__ pcoord)
{
    __shared__ int cur[1000];
    const int tid = threadIdx.x;
    for (int c = tid; c < 1000; c += 512) cur[c] = 0;
    __syncthreads();
    for (int p = blockIdx.x * 512 + tid; p < NPTS; p += NSB * 512) {
        int z = c0[p], y = c1[p], x = c2[p];
        int cell = (z >> 3) * 100 + (y >> 3) * 10 + (x >> 3);
        int r = atomicAdd(&cur[cell], 1);            // LDS atomic (fast)
        int pos = cs[cell] + blockbase[blockIdx.x * 1000 + cell] + r;
        perm[pos] = p;
        pcoord[pos] = z | (y << 8) | (x << 16);
    }
}

// ---------------- K2: conv2 -- cell-halo in LDS, barrier-free inner loop ----------------
// One block per 8x8x8 cell (grid 1000, 512 thr = 8 waves, each wave = 32 points x 64 oc).
// 10x10x10 halo (125 KB) loaded into LDS once (FETCH proven ~42 MB, round 5). Changes vs r5:
//  - 8M x 1N wave shape: each A fragment is read ONCE from LDS (was twice) -> LDS pressure
//    and bank conflicts halve.
//  - B read per-MFMA from global in dense fragment order (wpb repack): fully-coalesced 1 KB
//    loads, L1-resident 8 KB/offset -> no Blds, NO barriers in the 27-offset loop; waves
//    slip freely and hide each other's latency.
__global__ __launch_bounds__(512) void conv2_halo(
    const short* __restrict__ f1s, const short* __restrict__ wfb,
    const float* __restrict__ b2,
    const int* __restrict__ cs, const int* __restrict__ ce,
    const int* __restrict__ perm, const int* __restrict__ pcoord,
    const short* __restrict__ zeros,
    __hip_bfloat16* __restrict__ g)
{
    __shared__ short Alds[1000 * 64];    // 125 KB halo: row r, slot s holds chunk s^(r&7)

    // bijective XCD swizzle (1000 = 8*125)
    int bid = blockIdx.x;
    { const int xcd = bid & 7, i = bid >> 3; bid = xcd * 125 + i; }
    const int cell = bid;
    const int cz = cell / 100, cyx = cell - cz * 100;
    const int cy = cyx / 10, cx = cyx - cy * 10;

    const int tid = threadIdx.x;
    const int w = tid >> 6, lane = tid & 63;
    const int q = lane >> 4, lc = lane & 15;

    const int pstart = cs[cell], pend = ce[cell];

    // ---- halo load: 1000 rows, instr j covers rows 8j..8j+7 (1 KB, line-coalesced) ----
    const int pr = lane >> 3, pcs = lane & 7, ccs = pcs ^ pr;
    const int gz0 = cz * 8 - 1, gy0 = cy * 8 - 1, gx0 = cx * 8 - 1;
    for (int j = w; j < 125; j += 8) {
        int r = j * 8 + pr;
        int hz = r / 100; int rem = r - hz * 100;
        int hy = rem / 10; int hx = rem - hy * 10;
        int gz = gz0 + hz, gy = gy0 + hy, gx = gx0 + hx;
        const short* src = zeros + ccs * 8;
        if ((unsigned)gz < DD && (unsigned)gy < DD && (unsigned)gx < DD)
            src = f1s + (size_t)(gz * PLANE + gy * DD + gx) * 64 + ccs * 8;
        async_copy16(&Alds[j * 512], src);
    }
    asm volatile("s_waitcnt vmcnt(0)" ::: "memory");
    __syncthreads();   // the ONLY block-wide barrier

    float bias[4];
    #pragma unroll
    for (int nt = 0; nt < 4; nt++) bias[nt] = b2[nt * 16 + lc];

    // ---- chunks of 256 points (8 waves x 32); cells ~200 pts so usually one chunk ----
    for (int pb2 = pstart; pb2 < pend; pb2 += 256) {
        int hbase[2];
        #pragma unroll
        for (int mt = 0; mt < 2; mt++) {
            int p = pb2 + w * 32 + mt * 16 + lc;
            if (p >= pend) p = pend - 1;
            int pk = pcoord[p];
            int z = pk & 0xff, y = (pk >> 8) & 0xff, x = (pk >> 16) & 0xff;
            hbase[mt] = (z - gz0) * 100 + (y - gy0) * 10 + (x - gx0);
        }

        floatx4 acc[2][4];
        #pragma unroll
        for (int mt = 0; mt < 2; mt++)
            #pragma unroll
            for (int nt = 0; nt < 4; nt++)
                acc[mt][nt] = (floatx4){0.f, 0.f, 0.f, 0.f};

        #pragma unroll
        for (int off = 0; off < 27; ++off) {
            const int dz = off / 9, rem = off - dz * 9;
            const int dy = rem / 3, dx = rem - dy * 3;
            const int dh = (dz - 1) * 100 + (dy - 1) * 10 + (dx - 1);

            bf16x8 afr[2][2];
            #pragma unroll
            for (int mt = 0; mt < 2; mt++) {
                const int hrow = hbase[mt] + dh;             // in [0,1000)
                const int sw = hrow & 7;
                #pragma unroll
                for (int ks = 0; ks < 2; ks++)
                    afr[mt][ks] = *(const bf16x8*)(
                        &Alds[hrow * 64 + (((ks * 4 + q) ^ sw) << 3)]);
            }
            bf16x8 bfr[4][2];
            #pragma unroll
            for (int nt = 0; nt < 4; nt++)
                #pragma unroll
                for (int ks = 0; ks < 2; ks++)
                    bfr[nt][ks] = *(const bf16x8*)(
                        wfb + off * 4096 + nt * 1024 + ks * 512 + lane * 8);

            #pragma unroll
            for (int ks = 0; ks < 2; ks++)
                #pragma unroll
                for (int mt = 0; mt < 2; mt++)
                    #pragma unroll
                    for (int nt = 0; nt < 4; nt++)
                        acc[mt][nt] = __builtin_amdgcn_mfma_f32_16x16x32_bf16(
                            afr[mt][ks], bfr[nt][ks], acc[mt][nt], 0, 0, 0);
        }

        #pragma unroll
        for (int mt = 0; mt < 2; mt++) {
            const int pt = pb2 + w * 32 + mt * 16 + q * 4;
            #pragma unroll
            for (int r = 0; r < 4; r++) {
                if (pt + r < pend) {
                    const int orig = perm[pt + r];
                    #pragma unroll
                    for (int nt = 0; nt < 4; nt++) {
                        const int oc = nt * 16 + lc;
                        float v = acc[mt][nt][r] + bias[nt];
                        g[(size_t)orig * 64 + oc] = __float2bfloat16(v > 0.f ? v : 0.f);
                    }
                }
            }
        }
    }
}

// ---------------- K3: fused MLP via MFMA. block = 64 points, 4 waves split N ----------------
__global__ __launch_bounds__(256) void mlp_mfma(
    const __hip_bfloat16* __restrict__ g,
    const short* __restrict__ w1b, const float* __restrict__ bp1,
    const short* __restrict__ w2b, const float* __restrict__ bp2,
    const short* __restrict__ w3b, const float* __restrict__ bp3,
    const float* __restrict__ wp4, const float* __restrict__ bp4,
    float* __restrict__ out)
{
    __shared__ short bufA[64 * 256];   // 32 KB: X, then H2
    __shared__ short bufB[64 * 256];   // 32 KB: H1; then fp32 H3 overlay
    float* h3f = (float*)bufB;

    const int tid = threadIdx.x;
    const int pb = blockIdx.x * 64;
    const int w = tid >> 6, lane = tid & 63;
    const int q = lane >> 4, lc = lane & 15;

    const short* gs = (const short*)g;
    #pragma unroll
    for (int it = 0; it < 2; it++) {
        int idx = it * 256 + tid;
        int r = idx >> 3, c = idx & 7;
        int4 v = *(const int4*)(gs + (size_t)(pb + r) * 64 + c * 8);
        *(int4*)(&bufA[r * 256 + (c ^ (r & 7)) * 8]) = v;
    }
    __syncthreads();

    // L1: 64 -> 256, relu
    {
        floatx4 acc[4][4];
        #pragma unroll
        for (int mt = 0; mt < 4; mt++)
            #pragma unroll
            for (int nt = 0; nt < 4; nt++)
                acc[mt][nt] = (floatx4){0.f, 0.f, 0.f, 0.f};

        #pragma unroll
        for (int ks = 0; ks < 2; ks++) {
            bf16x8 bfr[4];
            #pragma unroll
            for (int nt = 0; nt < 4; nt++)
                bfr[nt] = *(const bf16x8*)(w1b + (w * 64 + nt * 16 + lc) * 64 + ks * 32 + q * 8);
            const int c = ks * 4 + q;
            #pragma unroll
            for (int mt = 0; mt < 4; mt++) {
                const int m = mt * 16 + lc;
                bf16x8 afr = *(const bf16x8*)(&bufA[m * 256 + (c ^ (m & 7)) * 8]);
                #pragma unroll
                for (int nt = 0; nt < 4; nt++)
                    acc[mt][nt] = __builtin_amdgcn_mfma_f32_16x16x32_bf16(afr, bfr[nt], acc[mt][nt], 0, 0, 0);
            }
        }
        float bias[4];
        #pragma unroll
        for (int nt = 0; nt < 4; nt++) bias[nt] = bp1[w * 64 + nt * 16 + lc];
        #pragma unroll
        for (int mt = 0; mt < 4; mt++)
            #pragma unroll
            for (int nt = 0; nt < 4; nt++) {
                const int col = w * 64 + nt * 16 + lc;
                #pragma unroll
                for (int r = 0; r < 4; r++) {
                    const int m = mt * 16 + q * 4 + r;
                    float v = acc[mt][nt][r] + bias[nt];
                    v = v > 0.f ? v : 0.f;
                    bufB[m * 256 + (((col >> 3) ^ (m & 7)) * 8 + (col & 7))] = f2bf(v);
                }
            }
    }
    __syncthreads();

    // L2: 256 -> 256, relu
    {
        floatx4 acc[4][4];
        #pragma unroll
        for (int mt = 0; mt < 4; mt++)
            #pragma unroll
            for (int nt = 0; nt < 4; nt++)
                acc[mt][nt] = (floatx4){0.f, 0.f, 0.f, 0.f};

        #pragma unroll
        for (int ks = 0; ks < 8; ks++) {
            bf16x8 bfr[4];
            #pragma unroll
            for (int nt = 0; nt < 4; nt++)
                bfr[nt] = *(const bf16x8*)(w2b + (w * 64 + nt * 16 + lc) * 256 + ks * 32 + q * 8);
            const int c = ks * 4 + q;
            #pragma unroll
            for (int mt = 0; mt < 4; mt++) {
                const int m = mt * 16 + lc;
                const int pc = (c & 24) | ((c & 7) ^ (m & 7));
                bf16x8 afr = *(const bf16x8*)(&bufB[m * 256 + pc * 8]);
                #pragma unroll
                for (int nt = 0; nt < 4; nt++)
                    acc[mt][nt] = __builtin_amdgcn_mfma_f32_16x16x32_bf16(afr, bfr[nt], acc[mt][nt], 0, 0, 0);
            }
        }
        float bias[4];
        #pragma unroll
        for (int nt = 0; nt < 4; nt++) bias[nt] = bp2[w * 64 + nt * 16 + lc];
        __syncthreads();
        #pragma unroll
        for (int mt = 0; mt < 4; mt++)
            #pragma unroll
            for (int nt = 0; nt < 4; nt++) {
                const int col = w * 64 + nt * 16 + lc;
                #pragma unroll
                for (int r = 0; r < 4; r++) {
                    const int m = mt * 16 + q * 4 + r;
                    float v = acc[mt][nt][r] + bias[nt];
                    v = v > 0.f ? v : 0.f;
                    bufA[m * 256 + (((col >> 3) ^ (m & 7)) * 8 + (col & 7))] = f2bf(v);
                }
            }
    }
    __syncthreads();

    // L3: 256 -> 64
    {
        floatx4 acc[4];
        #pragma unroll
        for (int mt = 0; mt < 4; mt++) acc[mt] = (floatx4){0.f, 0.f, 0.f, 0.f};

        #pragma unroll
        for (int ks = 0; ks < 8; ks++) {
            bf16x8 bfr = *(const bf16x8*)(w3b + (w * 16 + lc) * 256 + ks * 32 + q * 8);
            const int c = ks * 4 + q;
            #pragma unroll
            for (int mt = 0; mt < 4; mt++) {
                const int m = mt * 16 + lc;
                const int pc = (c & 24) | ((c & 7) ^ (m & 7));
                bf16x8 afr = *(const bf16x8*)(&bufA[m * 256 + pc * 8]);
                acc[mt] = __builtin_amdgcn_mfma_f32_16x16x32_bf16(afr, bfr, acc[mt], 0, 0, 0);
            }
        }
        const float bias = bp3[w * 16 + lc];
        const int col = w * 16 + lc;
        __syncthreads();
        #pragma unroll
        for (int mt = 0; mt < 4; mt++)
            #pragma unroll
            for (int r = 0; r < 4; r++) {
                const int m = mt * 16 + q * 4 + r;
                h3f[m * 65 + col] = acc[mt][r] + bias;
            }
    }
    __syncthreads();

    // L4: 64 -> 6
    for (int e = tid; e < 384; e += 256) {
        int c = e >> 6, p = e & 63;
        float a = bp4[c];
        const float* wr = wp4 + c * 64;
        const float* xr = h3f + p * 65;
        #pragma unroll 8
        for (int k = 0; k < 64; k++) a += wr[k] * xr[k];
        out[(size_t)c * NPTS + pb + p] = a;
    }
}

extern "C" void kernel_launch(void* const* d_in, const int* in_sizes, int n_in,
                              void* d_out, int out_size, void* d_ws, size_t ws_size,
                              hipStream_t stream) {
    const float* img = (const float*)d_in[0];
    const int* c0 = (const int*)d_in[1];
    const int* c1 = (const int*)d_in[2];
    const int* c2 = (const int*)d_in[3];
    const float* w_enc1 = (const float*)d_in[4];
    const float* b_enc1 = (const float*)d_in[5];
    const float* w_enc2 = (const float*)d_in[6];
    const float* b_enc2 = (const float*)d_in[7];
    const float* w_p1 = (const float*)d_in[8];
    const float* b_p1 = (const float*)d_in[9];
    const float* w_p2 = (const float*)d_in[10];
    const float* b_p2 = (const float*)d_in[11];
    const float* w_p3 = (const float*)d_in[12];
    const float* b_p3 = (const float*)d_in[13];
    const float* w_p4 = (const float*)d_in[14];
    const float* b_p4 = (const float*)d_in[15];
    float* out = (float*)d_out;

    short* f1b = (short*)d_ws;                       // 32,768,000
    short* wpb = f1b + (size_t)VOX * 64;             // 110592 (conv2 B, fragment order)
    short* w1b = wpb + 110592;                       // 16384
    short* w2b = w1b + 16384;                        // 65536
    short* w3b = w2b + 65536;                        // 16384
    short* gb  = w3b + 16384;                        // 12,800,000
    short* img_t = gb + (size_t)NPTS * 64;           // 16,384,000
    short* wc1 = img_t + (size_t)VOX * 32;           // 55296
    short* zeros = wc1 + 55296;                      // 64 shorts (128 B zero source)

    // sort arrays alias img_t (free after conv1 consumes it)
    int* perm      = (int*)img_t;                    // 200000
    int* pcoord    = perm + NPTS;                    // 200000
    int* partial   = pcoord + NPTS;                  // 64*1000
    int* blockbase = partial + 64 * 1000;            // 64*1000
    int* cstart    = blockbase + 64 * 1000;          // 1000
    int* cend      = cstart + 1000;                  // 1000

    hipMemsetAsync(zeros, 0, 128, stream);
    convert_weights<<<(264192 + 255) / 256, 256, 0, stream>>>(
        w_enc2, w_p1, w_p2, w_p3, w_enc1, wpb, w1b, w2b, w3b, wc1);
    transpose_img<<<(VOX + 255) / 256, 256, 0, stream>>>(img, img_t);
    conv1_mfma<<<DD * DD, 256, 0, stream>>>(img_t, wc1, b_enc1, zeros, f1b);

    // LDS-histogram counting sort into 8^3 cells (no global atomics)
    hist_cells<<<64, 512, 0, stream>>>(c0, c1, c2, partial);
    scan_cells<<<1, 1024, 0, stream>>>(partial, blockbase, cstart, cend);
    scatter_points<<<64, 512, 0, stream>>>(c0, c1, c2, cstart, blockbase, perm, pcoord);

    conv2_halo<<<1000, 512, 0, stream>>>(
        f1b, wpb, b_enc2, cstart, cend, perm, pcoord, zeros, (__hip_bfloat16*)gb);
    mlp_mfma<<<NPTS / 64, 256, 0, stream>>>(
        (const __hip_bfloat16*)gb, w1b, b_p1, w2b, b_p2, w3b, b_p3, w_p4, b_p4, out);
}

// Round 7
// 471.096 us; speedup vs baseline: 2.5380x; 2.5380x over previous
//
#include <hip/hip_runtime.h>
#include <hip/hip_bf16.h>

#define DD 80
#define CIN 32
#define PLANE (DD*DD)        // 6400
#define VOX (DD*DD*DD)       // 512000
#define NPTS 200000

typedef __attribute__((ext_vector_type(8))) short bf16x8;
typedef __attribute__((ext_vector_type(4))) float floatx4;

static __device__ __forceinline__ short f2bf(float v) {
    __hip_bfloat16 b = __float2bfloat16(v);
    return *(short*)&b;
}

// async global->LDS 16B copy: lane's 16B lands at ldsbase + lane*16 (wave-uniform base);
// the GLOBAL source address is per-lane.
static __device__ __forceinline__ void async_copy16(void* lds, const void* g) {
    __builtin_amdgcn_global_load_lds(
        (const __attribute__((address_space(1))) unsigned int*)g,
        (__attribute__((address_space(3))) unsigned int*)lds, 16, 0, 0);
}

// ---------------- K0: convert/permute all weights to bf16 ----------------
// wpb layout: [oc][off][ic]  (oc*1728 + off*64 + ic)  -- round-5 layout for LDS B staging
__global__ void convert_weights(const float* __restrict__ w2,
                                const float* __restrict__ w_p1,
                                const float* __restrict__ w_p2,
                                const float* __restrict__ w_p3,
                                const float* __restrict__ w_e1,
                                short* __restrict__ wpb, short* __restrict__ w1b,
                                short* __restrict__ w2b, short* __restrict__ w3b,
                                short* __restrict__ wc1) {
    int i = blockIdx.x * 256 + threadIdx.x;      // total 264192
    if (i < 110592) {
        int oc = i / 1728, j = i - oc * 1728;
        int off = j >> 6, ic = j & 63;
        wpb[i] = f2bf(w2[oc * 1728 + ic * 27 + off]);
    } else if (i < 110592 + 16384) {
        int j = i - 110592;
        w1b[j] = f2bf(w_p1[j]);
    } else if (i < 110592 + 16384 + 65536) {
        int j = i - 110592 - 16384;
        w2b[j] = f2bf(w_p2[j]);
    } else if (i < 110592 + 16384 + 65536 + 16384) {
        int j = i - 110592 - 16384 - 65536;
        w3b[j] = f2bf(w_p3[j]);
    } else if (i < 110592 + 16384 + 65536 + 16384 + 55296) {
        int j = i - (110592 + 16384 + 65536 + 16384);   // [off][oc][ic]
        int off = j / 2048, r = j - off * 2048;
        int oc = r >> 5, ic = r & 31;
        wc1[j] = f2bf(w_e1[(oc * 32 + ic) * 27 + off]);
    }
}

// ---------------- K0b: transpose img (32,VOX) fp32 -> img_t [vox][32] bf16 ----------------
__global__ __launch_bounds__(256) void transpose_img(
    const float* __restrict__ img, short* __restrict__ img_t)
{
    int v = blockIdx.x * 256 + threadIdx.x;
    if (v >= VOX) return;
    short row[32];
    #pragma unroll
    for (int ic = 0; ic < 32; ic++)
        row[ic] = f2bf(img[(size_t)ic * VOX + v]);
    int4* dst = (int4*)(img_t + (size_t)v * 32);
    #pragma unroll
    for (int c = 0; c < 4; c++) dst[c] = ((int4*)row)[c];
}

// ---------------- K1: conv1 via implicit-GEMM MFMA, async LDS staging ----------------
__global__ __launch_bounds__(256) void conv1_mfma(
    const short* __restrict__ img_t, const short* __restrict__ wc1,
    const float* __restrict__ b1, const short* __restrict__ zeros,
    short* __restrict__ f1)
{
    __shared__ short Alds[3072 * 16 / 2];   // 48 KB

    const int bh = blockIdx.x;
    const int d = bh / DD, h = bh - d * DD;
    const int tid = threadIdx.x;
    const int w = tid >> 6, lane = tid & 63;
    const int q = lane >> 4, lc = lane & 15;

    for (int i = 0; i < 12; i++) {
        int s = (w * 12 + i) * 64 + lane;      // slot 0..3071
        int row = s >> 2, c = s & 3;
        int cs = c ^ (row & 3);                // swizzled source chunk
        int rr = row / 82, v = row - rr * 82;
        int dz = rr / 3, dyy = rr - dz * 3;
        int zz = d + dz - 1, yy = h + dyy - 1, ww = v - 1;
        const short* src = zeros;
        if (row < 738 && (unsigned)zz < DD && (unsigned)yy < DD && (unsigned)ww < DD)
            src = img_t + ((size_t)(zz * PLANE + yy * DD + ww)) * 32 + cs * 8;
        async_copy16(&Alds[(w * 12 + i) * 512], src);
    }
    __syncthreads();

    floatx4 acc[5];
    #pragma unroll
    for (int mt = 0; mt < 5; mt++) acc[mt] = (floatx4){0.f, 0.f, 0.f, 0.f};

    #pragma unroll 3
    for (int off = 0; off < 27; ++off) {
        const int dz = off / 9, rem = off - dz * 9;
        const int dy = rem / 3, dx = rem - dy * 3;
        const int rr = dz * 3 + dy;
        bf16x8 bfr = *(const bf16x8*)(wc1 + ((off * 64 + w * 16 + lc) << 5) + q * 8);
        #pragma unroll
        for (int mt = 0; mt < 5; mt++) {
            const int vv = rr * 82 + mt * 16 + lc + dx;
            bf16x8 afr = *(const bf16x8*)(&Alds[vv * 32 + ((q ^ (vv & 3)) << 3)]);
            acc[mt] = __builtin_amdgcn_mfma_f32_16x16x32_bf16(afr, bfr, acc[mt], 0, 0, 0);
        }
    }

    const int oc = w * 16 + lc;
    const float bias = b1[oc];
    const size_t vbase = (size_t)(d * DD + h) * DD;
    #pragma unroll
    for (int mt = 0; mt < 5; mt++) {
        #pragma unroll
        for (int r = 0; r < 4; r++) {
            const int m = mt * 16 + q * 4 + r;
            float v = acc[mt][r] + bias;
            f1[(vbase + m) * 64 + oc] = f2bf(v > 0.f ? v : 0.f);
        }
    }
}

// ---------------- binning v3: LDS-histogram counting sort, [cell][block] partials ----------------
#define NSB 32   // sort blocks

__global__ __launch_bounds__(512) void hist_cells(
    const int* __restrict__ c0, const int* __restrict__ c1, const int* __restrict__ c2,
    int* __restrict__ partial)
{
    __shared__ int h[1000];
    const int tid = threadIdx.x;
    for (int c = tid; c < 1000; c += 512) h[c] = 0;
    __syncthreads();
    for (int p = blockIdx.x * 512 + tid; p < NPTS; p += NSB * 512) {
        int cell = (c0[p] >> 3) * 100 + (c1[p] >> 3) * 10 + (c2[p] >> 3);
        atomicAdd(&h[cell], 1);
    }
    __syncthreads();
    for (int c = tid; c < 1000; c += 512) partial[c * NSB + blockIdx.x] = h[c];
}

__global__ __launch_bounds__(1024) void scan_cells(
    const int* __restrict__ partial, int* __restrict__ blockbase,
    int* __restrict__ cs, int* __restrict__ ce)
{
    __shared__ int a[1024], b[1024];
    const int t = threadIdx.x;
    int sum = 0;
    if (t < 1000) {
        const int base = t * NSB;                    // contiguous 32-int run per cell
        int run = 0;
        #pragma unroll 8
        for (int bb = 0; bb < NSB; bb++) {
            blockbase[base + bb] = run;              // exclusive within-cell prefix
            run += partial[base + bb];
        }
        sum = run;
    }
    a[t] = sum;
    __syncthreads();
    int* src = a; int* dst = b;
    for (int d = 1; d < 1024; d <<= 1) {
        int v = src[t];
        if (t >= d) v += src[t - d];
        dst[t] = v;
        __syncthreads();
        int* tmp = src; src = dst; dst = tmp;
    }
    if (t < 1000) { cs[t] = src[t] - sum; ce[t] = src[t]; }
}

__global__ __launch_bounds__(512) void scatter_points(
    const int* __restrict__ c0, const int* __restrict__ c1, const int* __restrict__ c2,
    const int* __restrict__ cs, const int* __restrict__ blockbase,
    int* __restrict__ perm, int* __restrict__ pcoord)
{
    __shared__ int cur[1000];
    const int tid = threadIdx.x;
    for (int c = tid; c < 1000; c += 512) cur[c] = 0;
    __syncthreads();
    for (int p = blockIdx.x * 512 + tid; p < NPTS; p += NSB * 512) {
        int z = c0[p], y = c1[p], x = c2[p];
        int cell = (z >> 3) * 100 + (y >> 3) * 10 + (x >> 3);
        int r = atomicAdd(&cur[cell], 1);            // LDS atomic
        int pos = cs[cell] + blockbase[cell * NSB + blockIdx.x] + r;
        perm[pos] = p;
        pcoord[pos] = z | (y << 8) | (x << 16);
    }
}

// ---------------- K2: conv2 -- cell-halo in LDS (round-5 structure + group padding) ----------------
// One block per 8x8x8 cell (grid 1000, 512 thr = 8 waves: 4 M-groups x 2 N-groups).
// 10x10x10 halo loaded into LDS once. NEW: halo row-groups (8 rows = 1024 B, one staging
// instruction) are placed at stride 1056 B (+32 B pad) -> each group gets an 8-bank phase
// rotation (1056/4 == 8 mod 32). Combined with the slot-XOR this breaks the "every row
// starts at bank 0" pathology that produced 10.3M conflict cycles in round 5.
__global__ __launch_bounds__(512) void conv2_halo(
    const short* __restrict__ f1s, const short* __restrict__ wpb,
    const float* __restrict__ b2,
    const int* __restrict__ cs, const int* __restrict__ ce,
    const int* __restrict__ perm, const int* __restrict__ pcoord,
    const short* __restrict__ zeros,
    __hip_bfloat16* __restrict__ g)
{
    __shared__ short Alds[125 * 528];    // 132000 B: group j at j*528 shorts (1056 B stride)
    __shared__ short Blds[2][512 * 8];   // 16 KB: slot s holds chunk (s&7)^(oc&7) of oc=s>>3

    // bijective XCD swizzle (1000 = 8*125)
    int bid = blockIdx.x;
    { const int xcd = bid & 7, i = bid >> 3; bid = xcd * 125 + i; }
    const int cell = bid;
    const int cz = cell / 100, cyx = cell - cz * 100;
    const int cy = cyx / 10, cx = cyx - cy * 10;

    const int tid = threadIdx.x;
    const int w = tid >> 6, lane = tid & 63;
    const int q = lane >> 4, lc = lane & 15;
    const int wm = w >> 1, wn = w & 1;   // 4 M-groups x 2 N-groups

    const int pstart = cs[cell], pend = ce[cell];

    // ---- halo load: 1000 rows, instr j covers rows 8j..8j+7 (1 KB, line-coalesced) ----
    const int pr = lane >> 3, pcs = lane & 7, ccs = pcs ^ pr;   // row-in-group / slot / src chunk
    const int gz0 = cz * 8 - 1, gy0 = cy * 8 - 1, gx0 = cx * 8 - 1;
    for (int j = w; j < 125; j += 8) {
        int r = j * 8 + pr;
        int hz = r / 100; int rem = r - hz * 100;
        int hy = rem / 10; int hx = rem - hy * 10;
        int gz = gz0 + hz, gy = gy0 + hy, gx = gx0 + hx;
        const short* src = zeros + ccs * 8;
        if ((unsigned)gz < DD && (unsigned)gy < DD && (unsigned)gx < DD)
            src = f1s + (size_t)(gz * PLANE + gy * DD + gx) * 64 + ccs * 8;
        async_copy16(&Alds[j * 528], src);
    }

    // stage B(off) into buffer b: 1 instr per wave (8 waves cover 512 slots)
#define STAGE_B(off, b)                                                       \
    {                                                                         \
        int s_ = w * 64 + lane;                                               \
        int oc_ = s_ >> 3, cs_ = (s_ & 7) ^ (oc_ & 7);                        \
        async_copy16(&Blds[b][(w * 64) * 8],                                  \
                     wpb + oc_ * 1728 + (off) * 64 + cs_ * 8);                \
    }

    // ---- chunks of 256 points (cells ~200 pts; >256 is rare but handled) ----
    for (int pb2 = pstart; pb2 < pend; pb2 += 256) {
        int hbase[4];
        #pragma unroll
        for (int mt = 0; mt < 4; mt++) {
            int p = pb2 + wm * 64 + mt * 16 + lc;
            if (p >= pend) p = pend - 1;
            int pk = pcoord[p];
            int z = pk & 0xff, y = (pk >> 8) & 0xff, x = (pk >> 16) & 0xff;
            hbase[mt] = (z - gz0) * 100 + (y - gy0) * 10 + (x - gx0);
        }

        floatx4 acc[4][2];
        #pragma unroll
        for (int mt = 0; mt < 4; mt++)
            #pragma unroll
            for (int nt = 0; nt < 2; nt++)
                acc[mt][nt] = (floatx4){0.f, 0.f, 0.f, 0.f};

        STAGE_B(0, 0)
        asm volatile("s_waitcnt vmcnt(0)" ::: "memory");   // halo + B(0) landed (this wave)
        __syncthreads();                                    // ... and all waves'

        for (int off = 0; off < 27; ++off) {
            const int cur = off & 1;
            const int noff = (off + 1 < 27) ? off + 1 : 0;   // wrap keeps vmcnt uniform
            STAGE_B(noff, cur ^ 1)
            asm volatile("s_waitcnt vmcnt(1)" ::: "memory"); // B(off) landed; B(off+1) in flight
            __syncthreads();

            const int dz = off / 9, rem = off - dz * 9;
            const int dy = rem / 3, dx = rem - dy * 3;
            const int dh = (dz - 1) * 100 + (dy - 1) * 10 + (dx - 1);

            bf16x8 afr[4][2];
            #pragma unroll
            for (int mt = 0; mt < 4; mt++) {
                const int hrow = hbase[mt] + dh;             // in [0,1000)
                const int sw = hrow & 7;
                const int abase = (hrow >> 3) * 528 + sw * 64;
                afr[mt][0] = *(const bf16x8*)(&Alds[abase + ((q ^ sw) << 3)]);
                afr[mt][1] = *(const bf16x8*)(&Alds[abase + (((q + 4) ^ sw) << 3)]);
            }
            bf16x8 bfr[2][2];
            #pragma unroll
            for (int nt = 0; nt < 2; nt++) {
                const int oc = wn * 32 + nt * 16 + lc;
                #pragma unroll
                for (int ks = 0; ks < 2; ks++) {
                    const int slot = oc * 8 + ((ks * 4 + q) ^ (oc & 7));
                    bfr[nt][ks] = *(const bf16x8*)(&Blds[cur][slot * 8]);
                }
            }

            #pragma unroll
            for (int ks = 0; ks < 2; ks++)
                #pragma unroll
                for (int mt = 0; mt < 4; mt++)
                    #pragma unroll
                    for (int nt = 0; nt < 2; nt++)
                        acc[mt][nt] = __builtin_amdgcn_mfma_f32_16x16x32_bf16(
                            afr[mt][ks], bfr[nt][ks], acc[mt][nt], 0, 0, 0);

            __syncthreads();   // all reads of Blds[cur] done before it's restaged
        }

        float bias[2];
        #pragma unroll
        for (int nt = 0; nt < 2; nt++) bias[nt] = b2[wn * 32 + nt * 16 + lc];
        #pragma unroll
        for (int mt = 0; mt < 4; mt++) {
            const int pt = pb2 + wm * 64 + mt * 16 + q * 4;
            #pragma unroll
            for (int r = 0; r < 4; r++) {
                if (pt + r < pend) {
                    const int orig = perm[pt + r];
                    #pragma unroll
                    for (int nt = 0; nt < 2; nt++) {
                        const int oc = wn * 32 + nt * 16 + lc;
                        float v = acc[mt][nt][r] + bias[nt];
                        g[(size_t)orig * 64 + oc] = __float2bfloat16(v > 0.f ? v : 0.f);
                    }
                }
            }
        }
    }
#undef STAGE_B
}

// ---------------- K3: fused MLP via MFMA. block = 64 points, 4 waves split N ----------------
__global__ __launch_bounds__(256) void mlp_mfma(
    const __hip_bfloat16* __restrict__ g,
    const short* __restrict__ w1b, const float* __restrict__ bp1,
    const short* __restrict__ w2b, const float* __restrict__ bp2,
    const short* __restrict__ w3b, const float* __restrict__ bp3,
    const float* __restrict__ wp4, const float* __restrict__ bp4,
    float* __restrict__ out)
{
    __shared__ short bufA[64 * 256];   // 32 KB: X, then H2
    __shared__ short bufB[64 * 256];   // 32 KB: H1; then fp32 H3 overlay
    float* h3f = (float*)bufB;

    const int tid = threadIdx.x;
    const int pb = blockIdx.x * 64;
    const int w = tid >> 6, lane = tid & 63;
    const int q = lane >> 4, lc = lane & 15;

    const short* gs = (const short*)g;
    #pragma unroll
    for (int it = 0; it < 2; it++) {
        int idx = it * 256 + tid;
        int r = idx >> 3, c = idx & 7;
        int4 v = *(const int4*)(gs + (size_t)(pb + r) * 64 + c * 8);
        *(int4*)(&bufA[r * 256 + (c ^ (r & 7)) * 8]) = v;
    }
    __syncthreads();

    // L1: 64 -> 256, relu
    {
        floatx4 acc[4][4];
        #pragma unroll
        for (int mt = 0; mt < 4; mt++)
            #pragma unroll
            for (int nt = 0; nt < 4; nt++)
                acc[mt][nt] = (floatx4){0.f, 0.f, 0.f, 0.f};

        #pragma unroll
        for (int ks = 0; ks < 2; ks++) {
            bf16x8 bfr[4];
            #pragma unroll
            for (int nt = 0; nt < 4; nt++)
                bfr[nt] = *(const bf16x8*)(w1b + (w * 64 + nt * 16 + lc) * 64 + ks * 32 + q * 8);
            const int c = ks * 4 + q;
            #pragma unroll
            for (int mt = 0; mt < 4; mt++) {
                const int m = mt * 16 + lc;
                bf16x8 afr = *(const bf16x8*)(&bufA[m * 256 + (c ^ (m & 7)) * 8]);
                #pragma unroll
                for (int nt = 0; nt < 4; nt++)
                    acc[mt][nt] = __builtin_amdgcn_mfma_f32_16x16x32_bf16(afr, bfr[nt], acc[mt][nt], 0, 0, 0);
            }
        }
        float bias[4];
        #pragma unroll
        for (int nt = 0; nt < 4; nt++) bias[nt] = bp1[w * 64 + nt * 16 + lc];
        #pragma unroll
        for (int mt = 0; mt < 4; mt++)
            #pragma unroll
            for (int nt = 0; nt < 4; nt++) {
                const int col = w * 64 + nt * 16 + lc;
                #pragma unroll
                for (int r = 0; r < 4; r++) {
                    const int m = mt * 16 + q * 4 + r;
                    float v = acc[mt][nt][r] + bias[nt];
                    v = v > 0.f ? v : 0.f;
                    bufB[m * 256 + (((col >> 3) ^ (m & 7)) * 8 + (col & 7))] = f2bf(v);
                }
            }
    }
    __syncthreads();

    // L2: 256 -> 256, relu
    {
        floatx4 acc[4][4];
        #pragma unroll
        for (int mt = 0; mt < 4; mt++)
            #pragma unroll
            for (int nt = 0; nt < 4; nt++)
                acc[mt][nt] = (floatx4){0.f, 0.f, 0.f, 0.f};

        #pragma unroll
        for (int ks = 0; ks < 8; ks++) {
            bf16x8 bfr[4];
            #pragma unroll
            for (int nt = 0; nt < 4; nt++)
                bfr[nt] = *(const bf16x8*)(w2b + (w * 64 + nt * 16 + lc) * 256 + ks * 32 + q * 8);
            const int c = ks * 4 + q;
            #pragma unroll
            for (int mt = 0; mt < 4; mt++) {
                const int m = mt * 16 + lc;
                const int pc = (c & 24) | ((c & 7) ^ (m & 7));
                bf16x8 afr = *(const bf16x8*)(&bufB[m * 256 + pc * 8]);
                #pragma unroll
                for (int nt = 0; nt < 4; nt++)
                    acc[mt][nt] = __builtin_amdgcn_mfma_f32_16x16x32_bf16(afr, bfr[nt], acc[mt][nt], 0, 0, 0);
            }
        }
        float bias[4];
        #pragma unroll
        for (int nt = 0; nt < 4; nt++) bias[nt] = bp2[w * 64 + nt * 16 + lc];
        __syncthreads();
        #pragma unroll
        for (int mt = 0; mt < 4; mt++)
            #pragma unroll
            for (int nt = 0; nt < 4; nt++) {
                const int col = w * 64 + nt * 16 + lc;
                #pragma unroll
                for (int r = 0; r < 4; r++) {
                    const int m = mt * 16 + q * 4 + r;
                    float v = acc[mt][nt][r] + bias[nt];
                    v = v > 0.f ? v : 0.f;
                    bufA[m * 256 + (((col >> 3) ^ (m & 7)) * 8 + (col & 7))] = f2bf(v);
                }
            }
    }
    __syncthreads();

    // L3: 256 -> 64
    {
        floatx4 acc[4];
        #pragma unroll
        for (int mt = 0; mt < 4; mt++) acc[mt] = (floatx4){0.f, 0.f, 0.f, 0.f};

        #pragma unroll
        for (int ks = 0; ks < 8; ks++) {
            bf16x8 bfr = *(const bf16x8*)(w3b + (w * 16 + lc) * 256 + ks * 32 + q * 8);
            const int c = ks * 4 + q;
            #pragma unroll
            for (int mt = 0; mt < 4; mt++) {
                const int m = mt * 16 + lc;
                const int pc = (c & 24) | ((c & 7) ^ (m & 7));
                bf16x8 afr = *(const bf16x8*)(&bufA[m * 256 + pc * 8]);
                acc[mt] = __builtin_amdgcn_mfma_f32_16x16x32_bf16(afr, bfr, acc[mt], 0, 0, 0);
            }
        }
        const float bias = bp3[w * 16 + lc];
        const int col = w * 16 + lc;
        __syncthreads();
        #pragma unroll
        for (int mt = 0; mt < 4; mt++)
            #pragma unroll
            for (int r = 0; r < 4; r++) {
                const int m = mt * 16 + q * 4 + r;
                h3f[m * 65 + col] = acc[mt][r] + bias;
            }
    }
    __syncthreads();

    // L4: 64 -> 6
    for (int e = tid; e < 384; e += 256) {
        int c = e >> 6, p = e & 63;
        float a = bp4[c];
        const float* wr = wp4 + c * 64;
        const float* xr = h3f + p * 65;
        #pragma unroll 8
        for (int k = 0; k < 64; k++) a += wr[k] * xr[k];
        out[(size_t)c * NPTS + pb + p] = a;
    }
}

extern "C" void kernel_launch(void* const* d_in, const int* in_sizes, int n_in,
                              void* d_out, int out_size, void* d_ws, size_t ws_size,
                              hipStream_t stream) {
    const float* img = (const float*)d_in[0];
    const int* c0 = (const int*)d_in[1];
    const int* c1 = (const int*)d_in[2];
    const int* c2 = (const int*)d_in[3];
    const float* w_enc1 = (const float*)d_in[4];
    const float* b_enc1 = (const float*)d_in[5];
    const float* w_enc2 = (const float*)d_in[6];
    const float* b_enc2 = (const float*)d_in[7];
    const float* w_p1 = (const float*)d_in[8];
    const float* b_p1 = (const float*)d_in[9];
    const float* w_p2 = (const float*)d_in[10];
    const float* b_p2 = (const float*)d_in[11];
    const float* w_p3 = (const float*)d_in[12];
    const float* b_p3 = (const float*)d_in[13];
    const float* w_p4 = (const float*)d_in[14];
    const float* b_p4 = (const float*)d_in[15];
    float* out = (float*)d_out;

    short* f1b = (short*)d_ws;                       // 32,768,000
    short* wpb = f1b + (size_t)VOX * 64;             // 110592
    short* w1b = wpb + 110592;                       // 16384
    short* w2b = w1b + 16384;                        // 65536
    short* w3b = w2b + 65536;                        // 16384
    short* gb  = w3b + 16384;                        // 12,800,000
    short* img_t = gb + (size_t)NPTS * 64;           // 16,384,000
    short* wc1 = img_t + (size_t)VOX * 32;           // 55296
    short* zeros = wc1 + 55296;                      // 64 shorts (128 B zero source)

    // sort arrays alias img_t (free after conv1 consumes it)
    int* perm      = (int*)img_t;                    // 200000
    int* pcoord    = perm + NPTS;                    // 200000
    int* partial   = pcoord + NPTS;                  // 32*1000  [cell][block]
    int* blockbase = partial + NSB * 1000;           // 32*1000  [cell][block]
    int* cstart    = blockbase + NSB * 1000;         // 1000
    int* cend      = cstart + 1000;                  // 1000

    hipMemsetAsync(zeros, 0, 128, stream);
    convert_weights<<<(264192 + 255) / 256, 256, 0, stream>>>(
        w_enc2, w_p1, w_p2, w_p3, w_enc1, wpb, w1b, w2b, w3b, wc1);
    transpose_img<<<(VOX + 255) / 256, 256, 0, stream>>>(img, img_t);
    conv1_mfma<<<DD * DD, 256, 0, stream>>>(img_t, wc1, b_enc1, zeros, f1b);

    // LDS-histogram counting sort into 8^3 cells
    hist_cells<<<NSB, 512, 0, stream>>>(c0, c1, c2, partial);
    scan_cells<<<1, 1024, 0, stream>>>(partial, blockbase, cstart, cend);
    scatter_points<<<NSB, 512, 0, stream>>>(c0, c1, c2, cstart, blockbase, perm, pcoord);

    conv2_halo<<<1000, 512, 0, stream>>>(
        f1b, wpb, b_enc2, cstart, cend, perm, pcoord, zeros, (__hip_bfloat16*)gb);
    mlp_mfma<<<NPTS / 64, 256, 0, stream>>>(
        (const __hip_bfloat16*)gb, w1b, b_p1, w2b, b_p2, w3b, b_p3, w_p4, b_p4, out);
}

// Round 8
// 432.987 us; speedup vs baseline: 2.7614x; 1.0880x over previous
//
#include <hip/hip_runtime.h>
#include <hip/hip_bf16.h>

#define DD 80
#define CIN 32
#define PLANE (DD*DD)        // 6400
#define VOX (DD*DD*DD)       // 512000
#define NPTS 200000

typedef __attribute__((ext_vector_type(8))) short bf16x8;
typedef __attribute__((ext_vector_type(4))) float floatx4;

static __device__ __forceinline__ short f2bf(float v) {
    __hip_bfloat16 b = __float2bfloat16(v);
    return *(short*)&b;
}

// async global->LDS 16B copy: lane's 16B lands at ldsbase + lane*16 (wave-uniform base);
// the GLOBAL source address is per-lane.
static __device__ __forceinline__ void async_copy16(void* lds, const void* g) {
    __builtin_amdgcn_global_load_lds(
        (const __attribute__((address_space(1))) unsigned int*)g,
        (__attribute__((address_space(3))) unsigned int*)lds, 16, 0, 0);
}

// ---------------- K0: convert/permute all weights to bf16 ----------------
// wpb holds conv2 B in exact MFMA-fragment order: [off][nt][ks][lane][e]
// (lane -> oc = nt*16+(lane&15), ic = ks*32+(lane>>4)*8+e). One wave load of
// wpb + off*4096 + nt*1024 + ks*512 + lane*8 is a dense, coalesced 1 KB fragment.
__global__ void convert_weights(const float* __restrict__ w2,
                                const float* __restrict__ w_p1,
                                const float* __restrict__ w_p2,
                                const float* __restrict__ w_p3,
                                const float* __restrict__ w_e1,
                                short* __restrict__ wpb, short* __restrict__ w1b,
                                short* __restrict__ w2b, short* __restrict__ w3b,
                                short* __restrict__ wc1) {
    int i = blockIdx.x * 256 + threadIdx.x;      // total 264192
    if (i < 110592) {
        int off = i >> 12, r = i & 4095;
        int nt = r >> 10, r2 = r & 1023;
        int ks = r2 >> 9, r3 = r2 & 511;
        int lane = r3 >> 3, e = r3 & 7;
        int oc = nt * 16 + (lane & 15);
        int ic = ks * 32 + (lane >> 4) * 8 + e;
        wpb[i] = f2bf(w2[oc * 1728 + ic * 27 + off]);
    } else if (i < 110592 + 16384) {
        int j = i - 110592;
        w1b[j] = f2bf(w_p1[j]);
    } else if (i < 110592 + 16384 + 65536) {
        int j = i - 110592 - 16384;
        w2b[j] = f2bf(w_p2[j]);
    } else if (i < 110592 + 16384 + 65536 + 16384) {
        int j = i - 110592 - 16384 - 65536;
        w3b[j] = f2bf(w_p3[j]);
    } else if (i < 110592 + 16384 + 65536 + 16384 + 55296) {
        int j = i - (110592 + 16384 + 65536 + 16384);   // [off][oc][ic]
        int off = j / 2048, r = j - off * 2048;
        int oc = r >> 5, ic = r & 31;
        wc1[j] = f2bf(w_e1[(oc * 32 + ic) * 27 + off]);
    }
}

// ---------------- K0b: transpose img (32,VOX) fp32 -> img_t [vox][32] bf16 ----------------
__global__ __launch_bounds__(256) void transpose_img(
    const float* __restrict__ img, short* __restrict__ img_t)
{
    int v = blockIdx.x * 256 + threadIdx.x;
    if (v >= VOX) return;
    short row[32];
    #pragma unroll
    for (int ic = 0; ic < 32; ic++)
        row[ic] = f2bf(img[(size_t)ic * VOX + v]);
    int4* dst = (int4*)(img_t + (size_t)v * 32);
    #pragma unroll
    for (int c = 0; c < 4; c++) dst[c] = ((int4*)row)[c];
}

// ---------------- K1: conv1 via implicit-GEMM MFMA, async LDS staging ----------------
__global__ __launch_bounds__(256) void conv1_mfma(
    const short* __restrict__ img_t, const short* __restrict__ wc1,
    const float* __restrict__ b1, const short* __restrict__ zeros,
    short* __restrict__ f1)
{
    __shared__ short Alds[3072 * 16 / 2];   // 48 KB

    const int bh = blockIdx.x;
    const int d = bh / DD, h = bh - d * DD;
    const int tid = threadIdx.x;
    const int w = tid >> 6, lane = tid & 63;
    const int q = lane >> 4, lc = lane & 15;

    for (int i = 0; i < 12; i++) {
        int s = (w * 12 + i) * 64 + lane;      // slot 0..3071
        int row = s >> 2, c = s & 3;
        int cs = c ^ (row & 3);                // swizzled source chunk
        int rr = row / 82, v = row - rr * 82;
        int dz = rr / 3, dyy = rr - dz * 3;
        int zz = d + dz - 1, yy = h + dyy - 1, ww = v - 1;
        const short* src = zeros;
        if (row < 738 && (unsigned)zz < DD && (unsigned)yy < DD && (unsigned)ww < DD)
            src = img_t + ((size_t)(zz * PLANE + yy * DD + ww)) * 32 + cs * 8;
        async_copy16(&Alds[(w * 12 + i) * 512], src);
    }
    __syncthreads();

    floatx4 acc[5];
    #pragma unroll
    for (int mt = 0; mt < 5; mt++) acc[mt] = (floatx4){0.f, 0.f, 0.f, 0.f};

    #pragma unroll 3
    for (int off = 0; off < 27; ++off) {
        const int dz = off / 9, rem = off - dz * 9;
        const int dy = rem / 3, dx = rem - dy * 3;
        const int rr = dz * 3 + dy;
        bf16x8 bfr = *(const bf16x8*)(wc1 + ((off * 64 + w * 16 + lc) << 5) + q * 8);
        #pragma unroll
        for (int mt = 0; mt < 5; mt++) {
            const int vv = rr * 82 + mt * 16 + lc + dx;
            bf16x8 afr = *(const bf16x8*)(&Alds[vv * 32 + ((q ^ (vv & 3)) << 3)]);
            acc[mt] = __builtin_amdgcn_mfma_f32_16x16x32_bf16(afr, bfr, acc[mt], 0, 0, 0);
        }
    }

    const int oc = w * 16 + lc;
    const float bias = b1[oc];
    const size_t vbase = (size_t)(d * DD + h) * DD;
    #pragma unroll
    for (int mt = 0; mt < 5; mt++) {
        #pragma unroll
        for (int r = 0; r < 4; r++) {
            const int m = mt * 16 + q * 4 + r;
            float v = acc[mt][r] + bias;
            f1[(vbase + m) * 64 + oc] = f2bf(v > 0.f ? v : 0.f);
        }
    }
}

// ---------------- binning v3: LDS-histogram counting sort, [cell][block] partials ----------------
#define NSB 32   // sort blocks

__global__ __launch_bounds__(512) void hist_cells(
    const int* __restrict__ c0, const int* __restrict__ c1, const int* __restrict__ c2,
    int* __restrict__ partial)
{
    __shared__ int h[1000];
    const int tid = threadIdx.x;
    for (int c = tid; c < 1000; c += 512) h[c] = 0;
    __syncthreads();
    for (int p = blockIdx.x * 512 + tid; p < NPTS; p += NSB * 512) {
        int cell = (c0[p] >> 3) * 100 + (c1[p] >> 3) * 10 + (c2[p] >> 3);
        atomicAdd(&h[cell], 1);
    }
    __syncthreads();
    for (int c = tid; c < 1000; c += 512) partial[c * NSB + blockIdx.x] = h[c];
}

__global__ __launch_bounds__(1024) void scan_cells(
    const int* __restrict__ partial, int* __restrict__ blockbase,
    int* __restrict__ cs, int* __restrict__ ce)
{
    __shared__ int a[1024], b[1024];
    const int t = threadIdx.x;
    int sum = 0;
    if (t < 1000) {
        const int base = t * NSB;                    // contiguous 32-int run per cell
        int run = 0;
        #pragma unroll 8
        for (int bb = 0; bb < NSB; bb++) {
            blockbase[base + bb] = run;              // exclusive within-cell prefix
            run += partial[base + bb];
        }
        sum = run;
    }
    a[t] = sum;
    __syncthreads();
    int* src = a; int* dst = b;
    for (int d = 1; d < 1024; d <<= 1) {
        int v = src[t];
        if (t >= d) v += src[t - d];
        dst[t] = v;
        __syncthreads();
        int* tmp = src; src = dst; dst = tmp;
    }
    if (t < 1000) { cs[t] = src[t] - sum; ce[t] = src[t]; }
}

__global__ __launch_bounds__(512) void scatter_points(
    const int* __restrict__ c0, const int* __restrict__ c1, const int* __restrict__ c2,
    const int* __restrict__ cs, const int* __restrict__ blockbase,
    int* __restrict__ perm, int* __restrict__ pcoord)
{
    __shared__ int cur[1000];
    const int tid = threadIdx.x;
    for (int c = tid; c < 1000; c += 512) cur[c] = 0;
    __syncthreads();
    for (int p = blockIdx.x * 512 + tid; p < NPTS; p += NSB * 512) {
        int z = c0[p], y = c1[p], x = c2[p];
        int cell = (z >> 3) * 100 + (y >> 3) * 10 + (x >> 3);
        int r = atomicAdd(&cur[cell], 1);            // LDS atomic
        int pos = cs[cell] + blockbase[cell * NSB + blockIdx.x] + r;
        perm[pos] = p;
        pcoord[pos] = z | (y << 8) | (x << 16);
    }
}

// ---------------- K2: conv2 -- cell-halo in LDS, barrier-free inner loop, B in registers ----------------
// One block per 8x8x8 cell (grid 1000, 512 thr = 8 waves). Wave shape Wn=1: each wave owns
// 32 points x ALL 64 oc, so each A fragment is read from LDS by exactly one wave
// (A LDS traffic 32 KB/offset/block -- 3x less than round 7's 96 KB). B comes straight
// from global in dense fragment order (1 KB coalesced loads, 8 KB/offset L1-resident,
// shared by all blocks) -- no Blds, and the ONLY barrier is after the halo load. Waves
// run the 27-offset loop fully independently; VMEM carries B while LDS carries A.
// Loop kept rolled (#pragma unroll 3) -- round 6 proved full-unroll B-prefetch spills.
__global__ __launch_bounds__(512) void conv2_halo(
    const short* __restrict__ f1s, const short* __restrict__ wfb,
    const float* __restrict__ b2,
    const int* __restrict__ cs, const int* __restrict__ ce,
    const int* __restrict__ perm, const int* __restrict__ pcoord,
    const short* __restrict__ zeros,
    __hip_bfloat16* __restrict__ g)
{
    __shared__ short Alds[1000 * 64];    // 125 KB halo: row r, slot s holds chunk s^(r&7)

    // bijective XCD swizzle (1000 = 8*125)
    int bid = blockIdx.x;
    { const int xcd = bid & 7, i = bid >> 3; bid = xcd * 125 + i; }
    const int cell = bid;
    const int cz = cell / 100, cyx = cell - cz * 100;
    const int cy = cyx / 10, cx = cyx - cy * 10;

    const int tid = threadIdx.x;
    const int w = tid >> 6, lane = tid & 63;
    const int q = lane >> 4, lc = lane & 15;

    const int pstart = cs[cell], pend = ce[cell];

    // ---- halo load: 1000 rows, instr j covers rows 8j..8j+7 (1 KB, line-coalesced) ----
    const int pr = lane >> 3, pcs = lane & 7, ccs = pcs ^ pr;   // row-in-group / slot / src chunk
    const int gz0 = cz * 8 - 1, gy0 = cy * 8 - 1, gx0 = cx * 8 - 1;
    for (int j = w; j < 125; j += 8) {
        int r = j * 8 + pr;
        int hz = r / 100; int rem = r - hz * 100;
        int hy = rem / 10; int hx = rem - hy * 10;
        int gz = gz0 + hz, gy = gy0 + hy, gx = gx0 + hx;
        const short* src = zeros + ccs * 8;
        if ((unsigned)gz < DD && (unsigned)gy < DD && (unsigned)gx < DD)
            src = f1s + (size_t)(gz * PLANE + gy * DD + gx) * 64 + ccs * 8;
        async_copy16(&Alds[j * 512], src);
    }
    asm volatile("s_waitcnt vmcnt(0)" ::: "memory");
    __syncthreads();   // the ONLY block-wide barrier

    float bias[4];
    #pragma unroll
    for (int nt = 0; nt < 4; nt++) bias[nt] = b2[nt * 16 + lc];

    // ---- chunks of 256 points (8 waves x 32); cells ~200 pts so usually one chunk ----
    for (int pb2 = pstart; pb2 < pend; pb2 += 256) {
        int hbase[2];
        #pragma unroll
        for (int mt = 0; mt < 2; mt++) {
            int p = pb2 + w * 32 + mt * 16 + lc;
            if (p >= pend) p = pend - 1;
            int pk = pcoord[p];
            int z = pk & 0xff, y = (pk >> 8) & 0xff, x = (pk >> 16) & 0xff;
            hbase[mt] = (z - gz0) * 100 + (y - gy0) * 10 + (x - gx0);
        }

        floatx4 acc[2][4];
        #pragma unroll
        for (int mt = 0; mt < 2; mt++)
            #pragma unroll
            for (int nt = 0; nt < 4; nt++)
                acc[mt][nt] = (floatx4){0.f, 0.f, 0.f, 0.f};

        #pragma unroll 3
        for (int off = 0; off < 27; ++off) {
            const int dz = off / 9, rem = off - dz * 9;
            const int dy = rem / 3, dx = rem - dy * 3;
            const int dh = (dz - 1) * 100 + (dy - 1) * 10 + (dx - 1);

            // B fragments: dense coalesced 1 KB loads, L1-resident (same for all blocks)
            bf16x8 bfr[4][2];
            #pragma unroll
            for (int nt = 0; nt < 4; nt++)
                #pragma unroll
                for (int ks = 0; ks < 2; ks++)
                    bfr[nt][ks] = *(const bf16x8*)(
                        wfb + off * 4096 + nt * 1024 + ks * 512 + lane * 8);

            // A fragments: per-lane LDS gather from the halo
            bf16x8 afr[2][2];
            #pragma unroll
            for (int mt = 0; mt < 2; mt++) {
                const int hrow = hbase[mt] + dh;             // in [0,1000)
                const int sw = hrow & 7;
                #pragma unroll
                for (int ks = 0; ks < 2; ks++)
                    afr[mt][ks] = *(const bf16x8*)(
                        &Alds[hrow * 64 + (((ks * 4 + q) ^ sw) << 3)]);
            }

            #pragma unroll
            for (int ks = 0; ks < 2; ks++)
                #pragma unroll
                for (int mt = 0; mt < 2; mt++)
                    #pragma unroll
                    for (int nt = 0; nt < 4; nt++)
                        acc[mt][nt] = __builtin_amdgcn_mfma_f32_16x16x32_bf16(
                            afr[mt][ks], bfr[nt][ks], acc[mt][nt], 0, 0, 0);
        }

        #pragma unroll
        for (int mt = 0; mt < 2; mt++) {
            const int pt = pb2 + w * 32 + mt * 16 + q * 4;
            #pragma unroll
            for (int r = 0; r < 4; r++) {
                if (pt + r < pend) {
                    const int orig = perm[pt + r];
                    #pragma unroll
                    for (int nt = 0; nt < 4; nt++) {
                        const int oc = nt * 16 + lc;
                        float v = acc[mt][nt][r] + bias[nt];
                        g[(size_t)orig * 64 + oc] = __float2bfloat16(v > 0.f ? v : 0.f);
                    }
                }
            }
        }
    }
}

// ---------------- K3: fused MLP via MFMA. block = 64 points, 4 waves split N ----------------
__global__ __launch_bounds__(256) void mlp_mfma(
    const __hip_bfloat16* __restrict__ g,
    const short* __restrict__ w1b, const float* __restrict__ bp1,
    const short* __restrict__ w2b, const float* __restrict__ bp2,
    const short* __restrict__ w3b, const float* __restrict__ bp3,
    const float* __restrict__ wp4, const float* __restrict__ bp4,
    float* __restrict__ out)
{
    __shared__ short bufA[64 * 256];   // 32 KB: X, then H2
    __shared__ short bufB[64 * 256];   // 32 KB: H1; then fp32 H3 overlay
    float* h3f = (float*)bufB;

    const int tid = threadIdx.x;
    const int pb = blockIdx.x * 64;
    const int w = tid >> 6, lane = tid & 63;
    const int q = lane >> 4, lc = lane & 15;

    const short* gs = (const short*)g;
    #pragma unroll
    for (int it = 0; it < 2; it++) {
        int idx = it * 256 + tid;
        int r = idx >> 3, c = idx & 7;
        int4 v = *(const int4*)(gs + (size_t)(pb + r) * 64 + c * 8);
        *(int4*)(&bufA[r * 256 + (c ^ (r & 7)) * 8]) = v;
    }
    __syncthreads();

    // L1: 64 -> 256, relu
    {
        floatx4 acc[4][4];
        #pragma unroll
        for (int mt = 0; mt < 4; mt++)
            #pragma unroll
            for (int nt = 0; nt < 4; nt++)
                acc[mt][nt] = (floatx4){0.f, 0.f, 0.f, 0.f};

        #pragma unroll
        for (int ks = 0; ks < 2; ks++) {
            bf16x8 bfr[4];
            #pragma unroll
            for (int nt = 0; nt < 4; nt++)
                bfr[nt] = *(const bf16x8*)(w1b + (w * 64 + nt * 16 + lc) * 64 + ks * 32 + q * 8);
            const int c = ks * 4 + q;
            #pragma unroll
            for (int mt = 0; mt < 4; mt++) {
                const int m = mt * 16 + lc;
                bf16x8 afr = *(const bf16x8*)(&bufA[m * 256 + (c ^ (m & 7)) * 8]);
                #pragma unroll
                for (int nt = 0; nt < 4; nt++)
                    acc[mt][nt] = __builtin_amdgcn_mfma_f32_16x16x32_bf16(afr, bfr[nt], acc[mt][nt], 0, 0, 0);
            }
        }
        float bias[4];
        #pragma unroll
        for (int nt = 0; nt < 4; nt++) bias[nt] = bp1[w * 64 + nt * 16 + lc];
        #pragma unroll
        for (int mt = 0; mt < 4; mt++)
            #pragma unroll
            for (int nt = 0; nt < 4; nt++) {
                const int col = w * 64 + nt * 16 + lc;
                #pragma unroll
                for (int r = 0; r < 4; r++) {
                    const int m = mt * 16 + q * 4 + r;
                    float v = acc[mt][nt][r] + bias[nt];
                    v = v > 0.f ? v : 0.f;
                    bufB[m * 256 + (((col >> 3) ^ (m & 7)) * 8 + (col & 7))] = f2bf(v);
                }
            }
    }
    __syncthreads();

    // L2: 256 -> 256, relu
    {
        floatx4 acc[4][4];
        #pragma unroll
        for (int mt = 0; mt < 4; mt++)
            #pragma unroll
            for (int nt = 0; nt < 4; nt++)
                acc[mt][nt] = (floatx4){0.f, 0.f, 0.f, 0.f};

        #pragma unroll
        for (int ks = 0; ks < 8; ks++) {
            bf16x8 bfr[4];
            #pragma unroll
            for (int nt = 0; nt < 4; nt++)
                bfr[nt] = *(const bf16x8*)(w2b + (w * 64 + nt * 16 + lc) * 256 + ks * 32 + q * 8);
            const int c = ks * 4 + q;
            #pragma unroll
            for (int mt = 0; mt < 4; mt++) {
                const int m = mt * 16 + lc;
                const int pc = (c & 24) | ((c & 7) ^ (m & 7));
                bf16x8 afr = *(const bf16x8*)(&bufB[m * 256 + pc * 8]);
                #pragma unroll
                for (int nt = 0; nt < 4; nt++)
                    acc[mt][nt] = __builtin_amdgcn_mfma_f32_16x16x32_bf16(afr, bfr[nt], acc[mt][nt], 0, 0, 0);
            }
        }
        float bias[4];
        #pragma unroll
        for (int nt = 0; nt < 4; nt++) bias[nt] = bp2[w * 64 + nt * 16 + lc];
        __syncthreads();
        #pragma unroll
        for (int mt = 0; mt < 4; mt++)
            #pragma unroll
            for (int nt = 0; nt < 4; nt++) {
                const int col = w * 64 + nt * 16 + lc;
                #pragma unroll
                for (int r = 0; r < 4; r++) {
                    const int m = mt * 16 + q * 4 + r;
                    float v = acc[mt][nt][r] + bias[nt];
                    v = v > 0.f ? v : 0.f;
                    bufA[m * 256 + (((col >> 3) ^ (m & 7)) * 8 + (col & 7))] = f2bf(v);
                }
            }
    }
    __syncthreads();

    // L3: 256 -> 64
    {
        floatx4 acc[4];
        #pragma unroll
        for (int mt = 0; mt < 4; mt++) acc[mt] = (floatx4){0.f, 0.f, 0.f, 0.f};

        #pragma unroll
        for (int ks = 0; ks < 8; ks++) {
            bf16x8 bfr = *(const bf16x8*)(w3b + (w * 16 + lc) * 256 + ks * 32 + q * 8);
            const int c = ks * 4 + q;
            #pragma unroll
            for (int mt = 0; mt < 4; mt++) {
                const int m = mt * 16 + lc;
                const int pc = (c & 24) | ((c & 7) ^ (m & 7));
                bf16x8 afr = *(const bf16x8*)(&bufA[m * 256 + pc * 8]);
                acc[mt] = __builtin_amdgcn_mfma_f32_16x16x32_bf16(afr, bfr, acc[mt], 0, 0, 0);
            }
        }
        const float bias = bp3[w * 16 + lc];
        const int col = w * 16 + lc;
        __syncthreads();
        #pragma unroll
        for (int mt = 0; mt < 4; mt++)
            #pragma unroll
            for (int r = 0; r < 4; r++) {
                const int m = mt * 16 + q * 4 + r;
                h3f[m * 65 + col] = acc[mt][r] + bias;
            }
    }
    __syncthreads();

    // L4: 64 -> 6
    for (int e = tid; e < 384; e += 256) {
        int c = e >> 6, p = e & 63;
        float a = bp4[c];
        const float* wr = wp4 + c * 64;
        const float* xr = h3f + p * 65;
        #pragma unroll 8
        for (int k = 0; k < 64; k++) a += wr[k] * xr[k];
        out[(size_t)c * NPTS + pb + p] = a;
    }
}

extern "C" void kernel_launch(void* const* d_in, const int* in_sizes, int n_in,
                              void* d_out, int out_size, void* d_ws, size_t ws_size,
                              hipStream_t stream) {
    const float* img = (const float*)d_in[0];
    const int* c0 = (const int*)d_in[1];
    const int* c1 = (const int*)d_in[2];
    const int* c2 = (const int*)d_in[3];
    const float* w_enc1 = (const float*)d_in[4];
    const float* b_enc1 = (const float*)d_in[5];
    const float* w_enc2 = (const float*)d_in[6];
    const float* b_enc2 = (const float*)d_in[7];
    const float* w_p1 = (const float*)d_in[8];
    const float* b_p1 = (const float*)d_in[9];
    const float* w_p2 = (const float*)d_in[10];
    const float* b_p2 = (const float*)d_in[11];
    const float* w_p3 = (const float*)d_in[12];
    const float* b_p3 = (const float*)d_in[13];
    const float* w_p4 = (const float*)d_in[14];
    const float* b_p4 = (const float*)d_in[15];
    float* out = (float*)d_out;

    short* f1b = (short*)d_ws;                       // 32,768,000
    short* wpb = f1b + (size_t)VOX * 64;             // 110592 (conv2 B, fragment order)
    short* w1b = wpb + 110592;                       // 16384
    short* w2b = w1b + 16384;                        // 65536
    short* w3b = w2b + 65536;                        // 16384
    short* gb  = w3b + 16384;                        // 12,800,000
    short* img_t = gb + (size_t)NPTS * 64;           // 16,384,000
    short* wc1 = img_t + (size_t)VOX * 32;           // 55296
    short* zeros = wc1 + 55296;                      // 64 shorts (128 B zero source)

    // sort arrays alias img_t (free after conv1 consumes it)
    int* perm      = (int*)img_t;                    // 200000
    int* pcoord    = perm + NPTS;                    // 200000
    int* partial   = pcoord + NPTS;                  // 32*1000  [cell][block]
    int* blockbase = partial + NSB * 1000;           // 32*1000  [cell][block]
    int* cstart    = blockbase + NSB * 1000;         // 1000
    int* cend      = cstart + 1000;                  // 1000

    hipMemsetAsync(zeros, 0, 128, stream);
    convert_weights<<<(264192 + 255) / 256, 256, 0, stream>>>(
        w_enc2, w_p1, w_p2, w_p3, w_enc1, wpb, w1b, w2b, w3b, wc1);
    transpose_img<<<(VOX + 255) / 256, 256, 0, stream>>>(img, img_t);
    conv1_mfma<<<DD * DD, 256, 0, stream>>>(img_t, wc1, b_enc1, zeros, f1b);

    // LDS-histogram counting sort into 8^3 cells
    hist_cells<<<NSB, 512, 0, stream>>>(c0, c1, c2, partial);
    scan_cells<<<1, 1024, 0, stream>>>(partial, blockbase, cstart, cend);
    scatter_points<<<NSB, 512, 0, stream>>>(c0, c1, c2, cstart, blockbase, perm, pcoord);

    conv2_halo<<<1000, 512, 0, stream>>>(
        f1b, wpb, b_enc2, cstart, cend, perm, pcoord, zeros, (__hip_bfloat16*)gb);
    mlp_mfma<<<NPTS / 64, 256, 0, stream>>>(
        (const __hip_bfloat16*)gb, w1b, b_p1, w2b, b_p2, w3b, b_p3, w_p4, b_p4, out);
}

// Round 9
// 388.098 us; speedup vs baseline: 3.0808x; 1.1157x over previous
//
#include <hip/hip_runtime.h>
#include <hip/hip_bf16.h>

#define DD 80
#define CIN 32
#define PLANE (DD*DD)        // 6400
#define VOX (DD*DD*DD)       // 512000
#define NPTS 200000

typedef __attribute__((ext_vector_type(8))) short bf16x8;
typedef __attribute__((ext_vector_type(4))) float floatx4;
typedef __attribute__((ext_vector_type(4))) short s4v;

static __device__ __forceinline__ short f2bf(float v) {
    __hip_bfloat16 b = __float2bfloat16(v);
    return *(short*)&b;
}

// async global->LDS 16B copy: lane's 16B lands at ldsbase + lane*16 (wave-uniform base);
// the GLOBAL source address is per-lane.
static __device__ __forceinline__ void async_copy16(void* lds, const void* g) {
    __builtin_amdgcn_global_load_lds(
        (const __attribute__((address_space(1))) unsigned int*)g,
        (__attribute__((address_space(3))) unsigned int*)lds, 16, 0, 0);
}

// ---------------- K0: convert/permute all weights to bf16 ----------------
// wpb: conv2 B fragment order [off][nt][ks][lane][e] (unchanged from round 8).
// w1f/w2f/w3f: MLP weights as MFMA *A-operand* fragments for the TRANSPOSED compute
// C'[n][m] = W x H^T:  lane (q,lc) holds row n = base + lc, k = ks*32 + q*8 + e.
//   w1f: frag = (w*4+nt)*2+ks  (32 frags x 512)   n = w*64+nt*16+lc, K=64
//   w2f: frag = (w*4+nt)*8+ks  (128 frags x 512)  n = w*64+nt*16+lc, K=256
//   w3f: frag = w*8+ks         (32 frags x 512)   n = w*16+lc,       K=256
__global__ void convert_weights(const float* __restrict__ w2,
                                const float* __restrict__ w_p1,
                                const float* __restrict__ w_p2,
                                const float* __restrict__ w_p3,
                                const float* __restrict__ w_e1,
                                short* __restrict__ wpb, short* __restrict__ w1f,
                                short* __restrict__ w2f, short* __restrict__ w3f,
                                short* __restrict__ wc1) {
    int i = blockIdx.x * 256 + threadIdx.x;      // total 264192
    if (i < 110592) {
        int off = i >> 12, r = i & 4095;
        int nt = r >> 10, r2 = r & 1023;
        int ks = r2 >> 9, r3 = r2 & 511;
        int lane = r3 >> 3, e = r3 & 7;
        int oc = nt * 16 + (lane & 15);
        int ic = ks * 32 + (lane >> 4) * 8 + e;
        wpb[i] = f2bf(w2[oc * 1728 + ic * 27 + off]);
    } else if (i < 110592 + 16384) {
        int j = i - 110592;
        int frag = j >> 9, r3 = j & 511;
        int lane = r3 >> 3, e = r3 & 7;
        int ks = frag & 1, nt = (frag >> 1) & 3, w = frag >> 3;
        int n = w * 64 + nt * 16 + (lane & 15);
        int k = ks * 32 + (lane >> 4) * 8 + e;
        w1f[j] = f2bf(w_p1[n * 64 + k]);
    } else if (i < 110592 + 16384 + 65536) {
        int j = i - 110592 - 16384;
        int frag = j >> 9, r3 = j & 511;
        int lane = r3 >> 3, e = r3 & 7;
        int ks = frag & 7, nt = (frag >> 3) & 3, w = frag >> 5;
        int n = w * 64 + nt * 16 + (lane & 15);
        int k = ks * 32 + (lane >> 4) * 8 + e;
        w2f[j] = f2bf(w_p2[n * 256 + k]);
    } else if (i < 110592 + 16384 + 65536 + 16384) {
        int j = i - 110592 - 16384 - 65536;
        int frag = j >> 9, r3 = j & 511;
        int lane = r3 >> 3, e = r3 & 7;
        int ks = frag & 7, w = frag >> 3;
        int n = w * 16 + (lane & 15);
        int k = ks * 32 + (lane >> 4) * 8 + e;
        w3f[j] = f2bf(w_p3[n * 256 + k]);
    } else if (i < 110592 + 16384 + 65536 + 16384 + 55296) {
        int j = i - (110592 + 16384 + 65536 + 16384);   // [off][oc][ic]
        int off = j / 2048, r = j - off * 2048;
        int oc = r >> 5, ic = r & 31;
        wc1[j] = f2bf(w_e1[(oc * 32 + ic) * 27 + off]);
    }
}

// ---------------- K0b: transpose img (32,VOX) fp32 -> img_t [vox][32] bf16 ----------------
__global__ __launch_bounds__(256) void transpose_img(
    const float* __restrict__ img, short* __restrict__ img_t)
{
    int v = blockIdx.x * 256 + threadIdx.x;
    if (v >= VOX) return;
    short row[32];
    #pragma unroll
    for (int ic = 0; ic < 32; ic++)
        row[ic] = f2bf(img[(size_t)ic * VOX + v]);
    int4* dst = (int4*)(img_t + (size_t)v * 32);
    #pragma unroll
    for (int c = 0; c < 4; c++) dst[c] = ((int4*)row)[c];
}

// ---------------- K1: conv1 via implicit-GEMM MFMA, async LDS staging ----------------
__global__ __launch_bounds__(256) void conv1_mfma(
    const short* __restrict__ img_t, const short* __restrict__ wc1,
    const float* __restrict__ b1, const short* __restrict__ zeros,
    short* __restrict__ f1)
{
    __shared__ short Alds[3072 * 16 / 2];   // 48 KB

    const int bh = blockIdx.x;
    const int d = bh / DD, h = bh - d * DD;
    const int tid = threadIdx.x;
    const int w = tid >> 6, lane = tid & 63;
    const int q = lane >> 4, lc = lane & 15;

    for (int i = 0; i < 12; i++) {
        int s = (w * 12 + i) * 64 + lane;      // slot 0..3071
        int row = s >> 2, c = s & 3;
        int cs = c ^ (row & 3);                // swizzled source chunk
        int rr = row / 82, v = row - rr * 82;
        int dz = rr / 3, dyy = rr - dz * 3;
        int zz = d + dz - 1, yy = h + dyy - 1, ww = v - 1;
        const short* src = zeros;
        if (row < 738 && (unsigned)zz < DD && (unsigned)yy < DD && (unsigned)ww < DD)
            src = img_t + ((size_t)(zz * PLANE + yy * DD + ww)) * 32 + cs * 8;
        async_copy16(&Alds[(w * 12 + i) * 512], src);
    }
    __syncthreads();

    floatx4 acc[5];
    #pragma unroll
    for (int mt = 0; mt < 5; mt++) acc[mt] = (floatx4){0.f, 0.f, 0.f, 0.f};

    #pragma unroll 3
    for (int off = 0; off < 27; ++off) {
        const int dz = off / 9, rem = off - dz * 9;
        const int dy = rem / 3, dx = rem - dy * 3;
        const int rr = dz * 3 + dy;
        bf16x8 bfr = *(const bf16x8*)(wc1 + ((off * 64 + w * 16 + lc) << 5) + q * 8);
        #pragma unroll
        for (int mt = 0; mt < 5; mt++) {
            const int vv = rr * 82 + mt * 16 + lc + dx;
            bf16x8 afr = *(const bf16x8*)(&Alds[vv * 32 + ((q ^ (vv & 3)) << 3)]);
            acc[mt] = __builtin_amdgcn_mfma_f32_16x16x32_bf16(afr, bfr, acc[mt], 0, 0, 0);
        }
    }

    const int oc = w * 16 + lc;
    const float bias = b1[oc];
    const size_t vbase = (size_t)(d * DD + h) * DD;
    #pragma unroll
    for (int mt = 0; mt < 5; mt++) {
        #pragma unroll
        for (int r = 0; r < 4; r++) {
            const int m = mt * 16 + q * 4 + r;
            float v = acc[mt][r] + bias;
            f1[(vbase + m) * 64 + oc] = f2bf(v > 0.f ? v : 0.f);
        }
    }
}

// ---------------- binning v3: LDS-histogram counting sort, [cell][block] partials ----------------
#define NSB 32   // sort blocks

__global__ __launch_bounds__(512) void hist_cells(
    const int* __restrict__ c0, const int* __restrict__ c1, const int* __restrict__ c2,
    int* __restrict__ partial)
{
    __shared__ int h[1000];
    const int tid = threadIdx.x;
    for (int c = tid; c < 1000; c += 512) h[c] = 0;
    __syncthreads();
    for (int p = blockIdx.x * 512 + tid; p < NPTS; p += NSB * 512) {
        int cell = (c0[p] >> 3) * 100 + (c1[p] >> 3) * 10 + (c2[p] >> 3);
        atomicAdd(&h[cell], 1);
    }
    __syncthreads();
    for (int c = tid; c < 1000; c += 512) partial[c * NSB + blockIdx.x] = h[c];
}

__global__ __launch_bounds__(1024) void scan_cells(
    const int* __restrict__ partial, int* __restrict__ blockbase,
    int* __restrict__ cs, int* __restrict__ ce)
{
    __shared__ int a[1024], b[1024];
    const int t = threadIdx.x;
    int sum = 0;
    if (t < 1000) {
        const int base = t * NSB;                    // contiguous 32-int run per cell
        int run = 0;
        #pragma unroll 8
        for (int bb = 0; bb < NSB; bb++) {
            blockbase[base + bb] = run;              // exclusive within-cell prefix
            run += partial[base + bb];
        }
        sum = run;
    }
    a[t] = sum;
    __syncthreads();
    int* src = a; int* dst = b;
    for (int d = 1; d < 1024; d <<= 1) {
        int v = src[t];
        if (t >= d) v += src[t - d];
        dst[t] = v;
        __syncthreads();
        int* tmp = src; src = dst; dst = tmp;
    }
    if (t < 1000) { cs[t] = src[t] - sum; ce[t] = src[t]; }
}

__global__ __launch_bounds__(512) void scatter_points(
    const int* __restrict__ c0, const int* __restrict__ c1, const int* __restrict__ c2,
    const int* __restrict__ cs, const int* __restrict__ blockbase,
    int* __restrict__ perm, int* __restrict__ pcoord)
{
    __shared__ int cur[1000];
    const int tid = threadIdx.x;
    for (int c = tid; c < 1000; c += 512) cur[c] = 0;
    __syncthreads();
    for (int p = blockIdx.x * 512 + tid; p < NPTS; p += NSB * 512) {
        int z = c0[p], y = c1[p], x = c2[p];
        int cell = (z >> 3) * 100 + (y >> 3) * 10 + (x >> 3);
        int r = atomicAdd(&cur[cell], 1);            // LDS atomic
        int pos = cs[cell] + blockbase[cell * NSB + blockIdx.x] + r;
        perm[pos] = p;
        pcoord[pos] = z | (y << 8) | (x << 16);
    }
}

// ---------------- K2: conv2 -- cell-halo in LDS, barrier-free inner loop, B in registers ----------------
// (unchanged from round 8 -- conv2 is no longer the top kernel)
__global__ __launch_bounds__(512) void conv2_halo(
    const short* __restrict__ f1s, const short* __restrict__ wfb,
    const float* __restrict__ b2,
    const int* __restrict__ cs, const int* __restrict__ ce,
    const int* __restrict__ perm, const int* __restrict__ pcoord,
    const short* __restrict__ zeros,
    __hip_bfloat16* __restrict__ g)
{
    __shared__ short Alds[1000 * 64];    // 125 KB halo: row r, slot s holds chunk s^(r&7)

    // bijective XCD swizzle (1000 = 8*125)
    int bid = blockIdx.x;
    { const int xcd = bid & 7, i = bid >> 3; bid = xcd * 125 + i; }
    const int cell = bid;
    const int cz = cell / 100, cyx = cell - cz * 100;
    const int cy = cyx / 10, cx = cyx - cy * 10;

    const int tid = threadIdx.x;
    const int w = tid >> 6, lane = tid & 63;
    const int q = lane >> 4, lc = lane & 15;

    const int pstart = cs[cell], pend = ce[cell];

    // ---- halo load: 1000 rows, instr j covers rows 8j..8j+7 (1 KB, line-coalesced) ----
    const int pr = lane >> 3, pcs = lane & 7, ccs = pcs ^ pr;   // row-in-group / slot / src chunk
    const int gz0 = cz * 8 - 1, gy0 = cy * 8 - 1, gx0 = cx * 8 - 1;
    for (int j = w; j < 125; j += 8) {
        int r = j * 8 + pr;
        int hz = r / 100; int rem = r - hz * 100;
        int hy = rem / 10; int hx = rem - hy * 10;
        int gz = gz0 + hz, gy = gy0 + hy, gx = gx0 + hx;
        const short* src = zeros + ccs * 8;
        if ((unsigned)gz < DD && (unsigned)gy < DD && (unsigned)gx < DD)
            src = f1s + (size_t)(gz * PLANE + gy * DD + gx) * 64 + ccs * 8;
        async_copy16(&Alds[j * 512], src);
    }
    asm volatile("s_waitcnt vmcnt(0)" ::: "memory");
    __syncthreads();   // the ONLY block-wide barrier

    float bias[4];
    #pragma unroll
    for (int nt = 0; nt < 4; nt++) bias[nt] = b2[nt * 16 + lc];

    // ---- chunks of 256 points (8 waves x 32); cells ~200 pts so usually one chunk ----
    for (int pb2 = pstart; pb2 < pend; pb2 += 256) {
        int hbase[2];
        #pragma unroll
        for (int mt = 0; mt < 2; mt++) {
            int p = pb2 + w * 32 + mt * 16 + lc;
            if (p >= pend) p = pend - 1;
            int pk = pcoord[p];
            int z = pk & 0xff, y = (pk >> 8) & 0xff, x = (pk >> 16) & 0xff;
            hbase[mt] = (z - gz0) * 100 + (y - gy0) * 10 + (x - gx0);
        }

        floatx4 acc[2][4];
        #pragma unroll
        for (int mt = 0; mt < 2; mt++)
            #pragma unroll
            for (int nt = 0; nt < 4; nt++)
                acc[mt][nt] = (floatx4){0.f, 0.f, 0.f, 0.f};

        #pragma unroll 3
        for (int off = 0; off < 27; ++off) {
            const int dz = off / 9, rem = off - dz * 9;
            const int dy = rem / 3, dx = rem - dy * 3;
            const int dh = (dz - 1) * 100 + (dy - 1) * 10 + (dx - 1);

            // B fragments: dense coalesced 1 KB loads, L1-resident (same for all blocks)
            bf16x8 bfr[4][2];
            #pragma unroll
            for (int nt = 0; nt < 4; nt++)
                #pragma unroll
                for (int ks = 0; ks < 2; ks++)
                    bfr[nt][ks] = *(const bf16x8*)(
                        wfb + off * 4096 + nt * 1024 + ks * 512 + lane * 8);

            // A fragments: per-lane LDS gather from the halo
            bf16x8 afr[2][2];
            #pragma unroll
            for (int mt = 0; mt < 2; mt++) {
                const int hrow = hbase[mt] + dh;             // in [0,1000)
                const int sw = hrow & 7;
                #pragma unroll
                for (int ks = 0; ks < 2; ks++)
                    afr[mt][ks] = *(const bf16x8*)(
                        &Alds[hrow * 64 + (((ks * 4 + q) ^ sw) << 3)]);
            }

            #pragma unroll
            for (int ks = 0; ks < 2; ks++)
                #pragma unroll
                for (int mt = 0; mt < 2; mt++)
                    #pragma unroll
                    for (int nt = 0; nt < 4; nt++)
                        acc[mt][nt] = __builtin_amdgcn_mfma_f32_16x16x32_bf16(
                            afr[mt][ks], bfr[nt][ks], acc[mt][nt], 0, 0, 0);
        }

        #pragma unroll
        for (int mt = 0; mt < 2; mt++) {
            const int pt = pb2 + w * 32 + mt * 16 + q * 4;
            #pragma unroll
            for (int r = 0; r < 4; r++) {
                if (pt + r < pend) {
                    const int orig = perm[pt + r];
                    #pragma unroll
                    for (int nt = 0; nt < 4; nt++) {
                        const int oc = nt * 16 + lc;
                        float v = acc[mt][nt][r] + bias[nt];
                        g[(size_t)orig * 64 + oc] = __float2bfloat16(v > 0.f ? v : 0.f);
                    }
                }
            }
        }
    }
}

// ---------------- K3: fused MLP, TRANSPOSED compute C'[n][m] = W x H^T ----------------
// Weights are the A-operand (fragment-dense prepack, coalesced 1 KB loads); activations
// are the B-operand read as ds_read_b128 from [m][k] XOR-swizzled LDS (2-way, free).
// D-layout (col=lane&15=point, rows=q*4+r = 4 CONSECUTIVE k of the next layer) makes the
// epilogue 16 packed ds_write_b64 per lane instead of 64 scalar ds_write_b16 (4x fewer
// DS ops) -- this was the VALU/DS serial section (VALUBusy 21.6% > MfmaUtil 13%).
// L3 writes fp32 float4 to padded h3f; L4 stays scalar fp32 (numerically identical).
__global__ __launch_bounds__(256) void mlp_mfma(
    const __hip_bfloat16* __restrict__ g,
    const short* __restrict__ w1f, const float* __restrict__ bp1,
    const short* __restrict__ w2f, const float* __restrict__ bp2,
    const short* __restrict__ w3f, const float* __restrict__ bp3,
    const float* __restrict__ wp4, const float* __restrict__ bp4,
    float* __restrict__ out)
{
    __shared__ short Xls[64 * 64];      // 8 KB: X [m][64] chunk-swizzled
    __shared__ short Hb[2][64 * 256];   // 2 x 32 KB: H1, H2 [m][256] chunk-swizzled
    float* h3f = (float*)Hb[0];         // fp32 H3 overlay [64][68] (Hb[0] free after L2)

    const int tid = threadIdx.x;
    const int pb = blockIdx.x * 64;
    const int w = tid >> 6, lane = tid & 63;
    const int q = lane >> 4, lc = lane & 15;

    // stage X: g[pb+r][64] -> Xls[r][slot c^(r&7)]
    const short* gs = (const short*)g;
    #pragma unroll
    for (int it = 0; it < 2; it++) {
        int idx = it * 256 + tid;        // 512 chunks
        int r = idx >> 3, c = idx & 7;
        int4 v = *(const int4*)(gs + (size_t)(pb + r) * 64 + c * 8);
        *(int4*)(&Xls[r * 64 + (c ^ (r & 7)) * 8]) = v;
    }
    __syncthreads();

    // L1: H1'[n=256][m=64] = W1 x X^T, relu
    {
        floatx4 acc[4][4];   // [mtile][nt]
        #pragma unroll
        for (int mt = 0; mt < 4; mt++)
            #pragma unroll
            for (int nt = 0; nt < 4; nt++)
                acc[mt][nt] = (floatx4){0.f, 0.f, 0.f, 0.f};

        #pragma unroll
        for (int ks = 0; ks < 2; ks++) {
            bf16x8 wf[4];
            #pragma unroll
            for (int nt = 0; nt < 4; nt++)
                wf[nt] = *(const bf16x8*)(w1f + (((w * 4 + nt) * 2 + ks) << 9) + lane * 8);
            const int c = ks * 4 + q;
            #pragma unroll
            for (int mt = 0; mt < 4; mt++) {
                const int m = mt * 16 + lc;
                bf16x8 hf = *(const bf16x8*)(&Xls[m * 64 + ((c ^ (m & 7)) << 3)]);
                #pragma unroll
                for (int nt = 0; nt < 4; nt++)
                    acc[mt][nt] = __builtin_amdgcn_mfma_f32_16x16x32_bf16(wf[nt], hf, acc[mt][nt], 0, 0, 0);
            }
        }
        #pragma unroll
        for (int nt = 0; nt < 4; nt++) {
            const floatx4 bs = *(const floatx4*)(bp1 + w * 64 + nt * 16 + q * 4);
            const int chunk = w * 8 + nt * 2 + (q >> 1);
            #pragma unroll
            for (int mt = 0; mt < 4; mt++) {
                const int m = mt * 16 + lc;
                s4v hv;
                #pragma unroll
                for (int r = 0; r < 4; r++) {
                    float v = acc[mt][nt][r] + bs[r];
                    hv[r] = f2bf(v > 0.f ? v : 0.f);
                }
                *(s4v*)(&Hb[0][m * 256 + ((chunk ^ (m & 7)) << 3) + ((q & 1) << 2)]) = hv;
            }
        }
    }
    __syncthreads();

    // L2: H2'[n=256][m=64] = W2 x H1^T, relu
    {
        floatx4 acc[4][4];
        #pragma unroll
        for (int mt = 0; mt < 4; mt++)
            #pragma unroll
            for (int nt = 0; nt < 4; nt++)
                acc[mt][nt] = (floatx4){0.f, 0.f, 0.f, 0.f};

        #pragma unroll
        for (int ks = 0; ks < 8; ks++) {
            bf16x8 wf[4];
            #pragma unroll
            for (int nt = 0; nt < 4; nt++)
                wf[nt] = *(const bf16x8*)(w2f + (((w * 4 + nt) * 8 + ks) << 9) + lane * 8);
            const int c = ks * 4 + q;
            #pragma unroll
            for (int mt = 0; mt < 4; mt++) {
                const int m = mt * 16 + lc;
                bf16x8 hf = *(const bf16x8*)(&Hb[0][m * 256 + ((c ^ (m & 7)) << 3)]);
                #pragma unroll
                for (int nt = 0; nt < 4; nt++)
                    acc[mt][nt] = __builtin_amdgcn_mfma_f32_16x16x32_bf16(wf[nt], hf, acc[mt][nt], 0, 0, 0);
            }
        }
        #pragma unroll
        for (int nt = 0; nt < 4; nt++) {
            const floatx4 bs = *(const floatx4*)(bp2 + w * 64 + nt * 16 + q * 4);
            const int chunk = w * 8 + nt * 2 + (q >> 1);
            #pragma unroll
            for (int mt = 0; mt < 4; mt++) {
                const int m = mt * 16 + lc;
                s4v hv;
                #pragma unroll
                for (int r = 0; r < 4; r++) {
                    float v = acc[mt][nt][r] + bs[r];
                    hv[r] = f2bf(v > 0.f ? v : 0.f);
                }
                *(s4v*)(&Hb[1][m * 256 + ((chunk ^ (m & 7)) << 3) + ((q & 1) << 2)]) = hv;
            }
        }
    }
    __syncthreads();

    // L3: H3'[n=64][m=64] = W3 x H2^T (no relu) -> fp32 h3f[m][68]
    {
        floatx4 acc3[4];
        #pragma unroll
        for (int mt = 0; mt < 4; mt++) acc3[mt] = (floatx4){0.f, 0.f, 0.f, 0.f};

        #pragma unroll
        for (int ks = 0; ks < 8; ks++) {
            bf16x8 wf = *(const bf16x8*)(w3f + (((w * 8 + ks)) << 9) + lane * 8);
            const int c = ks * 4 + q;
            #pragma unroll
            for (int mt = 0; mt < 4; mt++) {
                const int m = mt * 16 + lc;
                bf16x8 hf = *(const bf16x8*)(&Hb[1][m * 256 + ((c ^ (m & 7)) << 3)]);
                acc3[mt] = __builtin_amdgcn_mfma_f32_16x16x32_bf16(wf, hf, acc3[mt], 0, 0, 0);
            }
        }
        const floatx4 bs = *(const floatx4*)(bp3 + w * 16 + q * 4);
        __syncthreads();   // all waves done reading Hb[0] region (L2) before h3f overlay write
        #pragma unroll
        for (int mt = 0; mt < 4; mt++) {
            const int m = mt * 16 + lc;
            floatx4 hv;
            #pragma unroll
            for (int r = 0; r < 4; r++) hv[r] = acc3[mt][r] + bs[r];
            *(floatx4*)(&h3f[m * 68 + w * 16 + q * 4]) = hv;
        }
    }
    __syncthreads();

    // L4: 64 -> 6 (scalar fp32, numerically identical to reference path)
    for (int e = tid; e < 384; e += 256) {
        int c = e >> 6, p = e & 63;
        float a = bp4[c];
        const float* wr = wp4 + c * 64;
        const float* xr = h3f + p * 68;
        #pragma unroll 8
        for (int k = 0; k < 64; k++) a += wr[k] * xr[k];
        out[(size_t)c * NPTS + pb + p] = a;
    }
}

extern "C" void kernel_launch(void* const* d_in, const int* in_sizes, int n_in,
                              void* d_out, int out_size, void* d_ws, size_t ws_size,
                              hipStream_t stream) {
    const float* img = (const float*)d_in[0];
    const int* c0 = (const int*)d_in[1];
    const int* c1 = (const int*)d_in[2];
    const int* c2 = (const int*)d_in[3];
    const float* w_enc1 = (const float*)d_in[4];
    const float* b_enc1 = (const float*)d_in[5];
    const float* w_enc2 = (const float*)d_in[6];
    const float* b_enc2 = (const float*)d_in[7];
    const float* w_p1 = (const float*)d_in[8];
    const float* b_p1 = (const float*)d_in[9];
    const float* w_p2 = (const float*)d_in[10];
    const float* b_p2 = (const float*)d_in[11];
    const float* w_p3 = (const float*)d_in[12];
    const float* b_p3 = (const float*)d_in[13];
    const float* w_p4 = (const float*)d_in[14];
    const float* b_p4 = (const float*)d_in[15];
    float* out = (float*)d_out;

    short* f1b = (short*)d_ws;                       // 32,768,000
    short* wpb = f1b + (size_t)VOX * 64;             // 110592 (conv2 B, fragment order)
    short* w1b = wpb + 110592;                       // 16384 (MLP L1 A-frags)
    short* w2b = w1b + 16384;                        // 65536 (MLP L2 A-frags)
    short* w3b = w2b + 65536;                        // 16384 (MLP L3 A-frags)
    short* gb  = w3b + 16384;                        // 12,800,000
    short* img_t = gb + (size_t)NPTS * 64;           // 16,384,000
    short* wc1 = img_t + (size_t)VOX * 32;           // 55296
    short* zeros = wc1 + 55296;                      // 64 shorts (128 B zero source)

    // sort arrays alias img_t (free after conv1 consumes it)
    int* perm      = (int*)img_t;                    // 200000
    int* pcoord    = perm + NPTS;                    // 200000
    int* partial   = pcoord + NPTS;                  // 32*1000  [cell][block]
    int* blockbase = partial + NSB * 1000;           // 32*1000  [cell][block]
    int* cstart    = blockbase + NSB * 1000;         // 1000
    int* cend      = cstart + 1000;                  // 1000

    hipMemsetAsync(zeros, 0, 128, stream);
    convert_weights<<<(264192 + 255) / 256, 256, 0, stream>>>(
        w_enc2, w_p1, w_p2, w_p3, w_enc1, wpb, w1b, w2b, w3b, wc1);
    transpose_img<<<(VOX + 255) / 256, 256, 0, stream>>>(img, img_t);
    conv1_mfma<<<DD * DD, 256, 0, stream>>>(img_t, wc1, b_enc1, zeros, f1b);

    // LDS-histogram counting sort into 8^3 cells
    hist_cells<<<NSB, 512, 0, stream>>>(c0, c1, c2, partial);
    scan_cells<<<1, 1024, 0, stream>>>(partial, blockbase, cstart, cend);
    scatter_points<<<NSB, 512, 0, stream>>>(c0, c1, c2, cstart, blockbase, perm, pcoord);

    conv2_halo<<<1000, 512, 0, stream>>>(
        f1b, wpb, b_enc2, cstart, cend, perm, pcoord, zeros, (__hip_bfloat16*)gb);
    mlp_mfma<<<NPTS / 64, 256, 0, stream>>>(
        (const __hip_bfloat16*)gb, w1b, b_p1, w2b, b_p2, w3b, b_p3, w_p4, b_p4, out);
}

// Round 10
// 377.604 us; speedup vs baseline: 3.1664x; 1.0278x over previous
//
#include <hip/hip_runtime.h>
#include <hip/hip_bf16.h>

#define DD 80
#define CIN 32
#define PLANE (DD*DD)        // 6400
#define VOX (DD*DD*DD)       // 512000
#define NPTS 200000

typedef __attribute__((ext_vector_type(8))) short bf16x8;
typedef __attribute__((ext_vector_type(4))) float floatx4;
typedef __attribute__((ext_vector_type(4))) short s4v;

static __device__ __forceinline__ short f2bf(float v) {
    __hip_bfloat16 b = __float2bfloat16(v);
    return *(short*)&b;
}

// async global->LDS 16B copy: lane's 16B lands at ldsbase + lane*16 (wave-uniform base);
// the GLOBAL source address is per-lane.
static __device__ __forceinline__ void async_copy16(void* lds, const void* g) {
    __builtin_amdgcn_global_load_lds(
        (const __attribute__((address_space(1))) unsigned int*)g,
        (__attribute__((address_space(3))) unsigned int*)lds, 16, 0, 0);
}

// ---------------- K0: convert/permute all weights to bf16 ----------------
// wpb: conv2 B fragment order [off][nt][ks][lane][e].
// w1f/w2f/w3f: MLP weights as MFMA *A-operand* fragments for the TRANSPOSED compute
// C'[n][m] = W x H^T:  lane (q,lc) holds row n = base + lc, k = ks*32 + q*8 + e.
__global__ void convert_weights(const float* __restrict__ w2,
                                const float* __restrict__ w_p1,
                                const float* __restrict__ w_p2,
                                const float* __restrict__ w_p3,
                                const float* __restrict__ w_e1,
                                short* __restrict__ wpb, short* __restrict__ w1f,
                                short* __restrict__ w2f, short* __restrict__ w3f,
                                short* __restrict__ wc1) {
    int i = blockIdx.x * 256 + threadIdx.x;      // total 264192
    if (i < 110592) {
        int off = i >> 12, r = i & 4095;
        int nt = r >> 10, r2 = r & 1023;
        int ks = r2 >> 9, r3 = r2 & 511;
        int lane = r3 >> 3, e = r3 & 7;
        int oc = nt * 16 + (lane & 15);
        int ic = ks * 32 + (lane >> 4) * 8 + e;
        wpb[i] = f2bf(w2[oc * 1728 + ic * 27 + off]);
    } else if (i < 110592 + 16384) {
        int j = i - 110592;
        int frag = j >> 9, r3 = j & 511;
        int lane = r3 >> 3, e = r3 & 7;
        int ks = frag & 1, nt = (frag >> 1) & 3, w = frag >> 3;
        int n = w * 64 + nt * 16 + (lane & 15);
        int k = ks * 32 + (lane >> 4) * 8 + e;
        w1f[j] = f2bf(w_p1[n * 64 + k]);
    } else if (i < 110592 + 16384 + 65536) {
        int j = i - 110592 - 16384;
        int frag = j >> 9, r3 = j & 511;
        int lane = r3 >> 3, e = r3 & 7;
        int ks = frag & 7, nt = (frag >> 3) & 3, w = frag >> 5;
        int n = w * 64 + nt * 16 + (lane & 15);
        int k = ks * 32 + (lane >> 4) * 8 + e;
        w2f[j] = f2bf(w_p2[n * 256 + k]);
    } else if (i < 110592 + 16384 + 65536 + 16384) {
        int j = i - 110592 - 16384 - 65536;
        int frag = j >> 9, r3 = j & 511;
        int lane = r3 >> 3, e = r3 & 7;
        int ks = frag & 7, w = frag >> 3;
        int n = w * 16 + (lane & 15);
        int k = ks * 32 + (lane >> 4) * 8 + e;
        w3f[j] = f2bf(w_p3[n * 256 + k]);
    } else if (i < 110592 + 16384 + 65536 + 16384 + 55296) {
        int j = i - (110592 + 16384 + 65536 + 16384);   // [off][oc][ic]
        int off = j / 2048, r = j - off * 2048;
        int oc = r >> 5, ic = r & 31;
        wc1[j] = f2bf(w_e1[(oc * 32 + ic) * 27 + off]);
    }
}

// ---------------- K0b: transpose img (32,VOX) fp32 -> img_t [vox][32] bf16 ----------------
__global__ __launch_bounds__(256) void transpose_img(
    const float* __restrict__ img, short* __restrict__ img_t)
{
    int v = blockIdx.x * 256 + threadIdx.x;
    if (v >= VOX) return;
    short row[32];
    #pragma unroll
    for (int ic = 0; ic < 32; ic++)
        row[ic] = f2bf(img[(size_t)ic * VOX + v]);
    int4* dst = (int4*)(img_t + (size_t)v * 32);
    #pragma unroll
    for (int c = 0; c < 4; c++) dst[c] = ((int4*)row)[c];
}

// ---------------- K1: conv1 via implicit-GEMM MFMA, async LDS staging ----------------
// Round-10 changes (counters: SQ_LDS_BANK_CONFLICT 1.38e7, VALUBusy 42%):
//  (a) chunk swizzle S(row) = (row>>1)&3 (was row&3): bank-quad position becomes a
//      function of row mod 8 covering all 8 positions -> A-reads drop from 4-way
//      conflict to 2-way (free). Applied to BOTH staging source and read (same involution).
//  (b) off-loop restructured as nested dz/dy/dx (identical enumeration): deletes the
//      /9 /3 %3 constant-division mul_hi chains that dominated VALUBusy.
__global__ __launch_bounds__(256) void conv1_mfma(
    const short* __restrict__ img_t, const short* __restrict__ wc1,
    const float* __restrict__ b1, const short* __restrict__ zeros,
    short* __restrict__ f1)
{
    __shared__ short Alds[3072 * 16 / 2];   // 48 KB

    const int bh = blockIdx.x;
    const int d = bh / DD, h = bh - d * DD;
    const int tid = threadIdx.x;
    const int w = tid >> 6, lane = tid & 63;
    const int q = lane >> 4, lc = lane & 15;

    for (int i = 0; i < 12; i++) {
        int s = (w * 12 + i) * 64 + lane;      // slot 0..3071
        int row = s >> 2, c = s & 3;
        int cs = c ^ ((row >> 1) & 3);         // swizzled source chunk (mod-8 spread)
        int rr = row / 82, v = row - rr * 82;
        int dz = rr / 3, dyy = rr - dz * 3;
        int zz = d + dz - 1, yy = h + dyy - 1, ww = v - 1;
        const short* src = zeros;
        if (row < 738 && (unsigned)zz < DD && (unsigned)yy < DD && (unsigned)ww < DD)
            src = img_t + ((size_t)(zz * PLANE + yy * DD + ww)) * 32 + cs * 8;
        async_copy16(&Alds[(w * 12 + i) * 512], src);
    }
    __syncthreads();

    floatx4 acc[5];
    #pragma unroll
    for (int mt = 0; mt < 5; mt++) acc[mt] = (floatx4){0.f, 0.f, 0.f, 0.f};

    for (int dz = 0; dz < 3; dz++) {
        for (int dy = 0; dy < 3; dy++) {
            const int rr = dz * 3 + dy;
            #pragma unroll
            for (int dx = 0; dx < 3; dx++) {
                const int off = rr * 3 + dx;
                bf16x8 bfr = *(const bf16x8*)(wc1 + ((off * 64 + w * 16 + lc) << 5) + q * 8);
                #pragma unroll
                for (int mt = 0; mt < 5; mt++) {
                    const int vv = rr * 82 + mt * 16 + lc + dx;
                    bf16x8 afr = *(const bf16x8*)(
                        &Alds[vv * 32 + ((q ^ ((vv >> 1) & 3)) << 3)]);
                    acc[mt] = __builtin_amdgcn_mfma_f32_16x16x32_bf16(afr, bfr, acc[mt], 0, 0, 0);
                }
            }
        }
    }

    const int oc = w * 16 + lc;
    const float bias = b1[oc];
    const size_t vbase = (size_t)(d * DD + h) * DD;
    #pragma unroll
    for (int mt = 0; mt < 5; mt++) {
        #pragma unroll
        for (int r = 0; r < 4; r++) {
            const int m = mt * 16 + q * 4 + r;
            float v = acc[mt][r] + bias;
            f1[(vbase + m) * 64 + oc] = f2bf(v > 0.f ? v : 0.f);
        }
    }
}

// ---------------- binning v3: LDS-histogram counting sort, [cell][block] partials ----------------
#define NSB 32   // sort blocks

__global__ __launch_bounds__(512) void hist_cells(
    const int* __restrict__ c0, const int* __restrict__ c1, const int* __restrict__ c2,
    int* __restrict__ partial)
{
    __shared__ int h[1000];
    const int tid = threadIdx.x;
    for (int c = tid; c < 1000; c += 512) h[c] = 0;
    __syncthreads();
    for (int p = blockIdx.x * 512 + tid; p < NPTS; p += NSB * 512) {
        int cell = (c0[p] >> 3) * 100 + (c1[p] >> 3) * 10 + (c2[p] >> 3);
        atomicAdd(&h[cell], 1);
    }
    __syncthreads();
    for (int c = tid; c < 1000; c += 512) partial[c * NSB + blockIdx.x] = h[c];
}

__global__ __launch_bounds__(1024) void scan_cells(
    const int* __restrict__ partial, int* __restrict__ blockbase,
    int* __restrict__ cs, int* __restrict__ ce)
{
    __shared__ int a[1024], b[1024];
    const int t = threadIdx.x;
    int sum = 0;
    if (t < 1000) {
        const int base = t * NSB;                    // contiguous 32-int run per cell
        int run = 0;
        #pragma unroll 8
        for (int bb = 0; bb < NSB; bb++) {
            blockbase[base + bb] = run;              // exclusive within-cell prefix
            run += partial[base + bb];
        }
        sum = run;
    }
    a[t] = sum;
    __syncthreads();
    int* src = a; int* dst = b;
    for (int d = 1; d < 1024; d <<= 1) {
        int v = src[t];
        if (t >= d) v += src[t - d];
        dst[t] = v;
        __syncthreads();
        int* tmp = src; src = dst; dst = tmp;
    }
    if (t < 1000) { cs[t] = src[t] - sum; ce[t] = src[t]; }
}

__global__ __launch_bounds__(512) void scatter_points(
    const int* __restrict__ c0, const int* __restrict__ c1, const int* __restrict__ c2,
    const int* __restrict__ cs, const int* __restrict__ blockbase,
    int* __restrict__ perm, int* __restrict__ pcoord)
{
    __shared__ int cur[1000];
    const int tid = threadIdx.x;
    for (int c = tid; c < 1000; c += 512) cur[c] = 0;
    __syncthreads();
    for (int p = blockIdx.x * 512 + tid; p < NPTS; p += NSB * 512) {
        int z = c0[p], y = c1[p], x = c2[p];
        int cell = (z >> 3) * 100 + (y >> 3) * 10 + (x >> 3);
        int r = atomicAdd(&cur[cell], 1);            // LDS atomic
        int pos = cs[cell] + blockbase[cell * NSB + blockIdx.x] + r;
        perm[pos] = p;
        pcoord[pos] = z | (y << 8) | (x << 16);
    }
}

// ---------------- K2: conv2 -- cell-halo in LDS, barrier-free inner loop, B in registers ----------------
__global__ __launch_bounds__(512) void conv2_halo(
    const short* __restrict__ f1s, const short* __restrict__ wfb,
    const float* __restrict__ b2,
    const int* __restrict__ cs, const int* __restrict__ ce,
    const int* __restrict__ perm, const int* __restrict__ pcoord,
    const short* __restrict__ zeros,
    __hip_bfloat16* __restrict__ g)
{
    __shared__ short Alds[1000 * 64];    // 125 KB halo: row r, slot s holds chunk s^(r&7)

    // bijective XCD swizzle (1000 = 8*125)
    int bid = blockIdx.x;
    { const int xcd = bid & 7, i = bid >> 3; bid = xcd * 125 + i; }
    const int cell = bid;
    const int cz = cell / 100, cyx = cell - cz * 100;
    const int cy = cyx / 10, cx = cyx - cy * 10;

    const int tid = threadIdx.x;
    const int w = tid >> 6, lane = tid & 63;
    const int q = lane >> 4, lc = lane & 15;

    const int pstart = cs[cell], pend = ce[cell];

    // ---- halo load: 1000 rows, instr j covers rows 8j..8j+7 (1 KB, line-coalesced) ----
    const int pr = lane >> 3, pcs = lane & 7, ccs = pcs ^ pr;   // row-in-group / slot / src chunk
    const int gz0 = cz * 8 - 1, gy0 = cy * 8 - 1, gx0 = cx * 8 - 1;
    for (int j = w; j < 125; j += 8) {
        int r = j * 8 + pr;
        int hz = r / 100; int rem = r - hz * 100;
        int hy = rem / 10; int hx = rem - hy * 10;
        int gz = gz0 + hz, gy = gy0 + hy, gx = gx0 + hx;
        const short* src = zeros + ccs * 8;
        if ((unsigned)gz < DD && (unsigned)gy < DD && (unsigned)gx < DD)
            src = f1s + (size_t)(gz * PLANE + gy * DD + gx) * 64 + ccs * 8;
        async_copy16(&Alds[j * 512], src);
    }
    asm volatile("s_waitcnt vmcnt(0)" ::: "memory");
    __syncthreads();   // the ONLY block-wide barrier

    float bias[4];
    #pragma unroll
    for (int nt = 0; nt < 4; nt++) bias[nt] = b2[nt * 16 + lc];

    // ---- chunks of 256 points (8 waves x 32); cells ~200 pts so usually one chunk ----
    for (int pb2 = pstart; pb2 < pend; pb2 += 256) {
        int hbase[2];
        #pragma unroll
        for (int mt = 0; mt < 2; mt++) {
            int p = pb2 + w * 32 + mt * 16 + lc;
            if (p >= pend) p = pend - 1;
            int pk = pcoord[p];
            int z = pk & 0xff, y = (pk >> 8) & 0xff, x = (pk >> 16) & 0xff;
            hbase[mt] = (z - gz0) * 100 + (y - gy0) * 10 + (x - gx0);
        }

        floatx4 acc[2][4];
        #pragma unroll
        for (int mt = 0; mt < 2; mt++)
            #pragma unroll
            for (int nt = 0; nt < 4; nt++)
                acc[mt][nt] = (floatx4){0.f, 0.f, 0.f, 0.f};

        #pragma unroll 3
        for (int off = 0; off < 27; ++off) {
            const int dz = off / 9, rem = off - dz * 9;
            const int dy = rem / 3, dx = rem - dy * 3;
            const int dh = (dz - 1) * 100 + (dy - 1) * 10 + (dx - 1);

            // B fragments: dense coalesced 1 KB loads, L1-resident (same for all blocks)
            bf16x8 bfr[4][2];
            #pragma unroll
            for (int nt = 0; nt < 4; nt++)
                #pragma unroll
                for (int ks = 0; ks < 2; ks++)
                    bfr[nt][ks] = *(const bf16x8*)(
                        wfb + off * 4096 + nt * 1024 + ks * 512 + lane * 8);

            // A fragments: per-lane LDS gather from the halo
            bf16x8 afr[2][2];
            #pragma unroll
            for (int mt = 0; mt < 2; mt++) {
                const int hrow = hbase[mt] + dh;             // in [0,1000)
                const int sw = hrow & 7;
                #pragma unroll
                for (int ks = 0; ks < 2; ks++)
                    afr[mt][ks] = *(const bf16x8*)(
                        &Alds[hrow * 64 + (((ks * 4 + q) ^ sw) << 3)]);
            }

            #pragma unroll
            for (int ks = 0; ks < 2; ks++)
                #pragma unroll
                for (int mt = 0; mt < 2; mt++)
                    #pragma unroll
                    for (int nt = 0; nt < 4; nt++)
                        acc[mt][nt] = __builtin_amdgcn_mfma_f32_16x16x32_bf16(
                            afr[mt][ks], bfr[nt][ks], acc[mt][nt], 0, 0, 0);
        }

        #pragma unroll
        for (int mt = 0; mt < 2; mt++) {
            const int pt = pb2 + w * 32 + mt * 16 + q * 4;
            #pragma unroll
            for (int r = 0; r < 4; r++) {
                if (pt + r < pend) {
                    const int orig = perm[pt + r];
                    #pragma unroll
                    for (int nt = 0; nt < 4; nt++) {
                        const int oc = nt * 16 + lc;
                        float v = acc[mt][nt][r] + bias[nt];
                        g[(size_t)orig * 64 + oc] = __float2bfloat16(v > 0.f ? v : 0.f);
                    }
                }
            }
        }
    }
}

// ---------------- K3: fused MLP, TRANSPOSED compute C'[n][m] = W x H^T ----------------
__global__ __launch_bounds__(256) void mlp_mfma(
    const __hip_bfloat16* __restrict__ g,
    const short* __restrict__ w1f, const float* __restrict__ bp1,
    const short* __restrict__ w2f, const float* __restrict__ bp2,
    const short* __restrict__ w3f, const float* __restrict__ bp3,
    const float* __restrict__ wp4, const float* __restrict__ bp4,
    float* __restrict__ out)
{
    __shared__ short Xls[64 * 64];      // 8 KB: X [m][64] chunk-swizzled
    __shared__ short Hb[2][64 * 256];   // 2 x 32 KB: H1, H2 [m][256] chunk-swizzled
    float* h3f = (float*)Hb[0];         // fp32 H3 overlay [64][68] (Hb[0] free after L2)

    const int tid = threadIdx.x;
    const int pb = blockIdx.x * 64;
    const int w = tid >> 6, lane = tid & 63;
    const int q = lane >> 4, lc = lane & 15;

    // stage X: g[pb+r][64] -> Xls[r][slot c^(r&7)]
    const short* gs = (const short*)g;
    #pragma unroll
    for (int it = 0; it < 2; it++) {
        int idx = it * 256 + tid;        // 512 chunks
        int r = idx >> 3, c = idx & 7;
        int4 v = *(const int4*)(gs + (size_t)(pb + r) * 64 + c * 8);
        *(int4*)(&Xls[r * 64 + (c ^ (r & 7)) * 8]) = v;
    }
    __syncthreads();

    // L1: H1'[n=256][m=64] = W1 x X^T, relu
    {
        floatx4 acc[4][4];   // [mtile][nt]
        #pragma unroll
        for (int mt = 0; mt < 4; mt++)
            #pragma unroll
            for (int nt = 0; nt < 4; nt++)
                acc[mt][nt] = (floatx4){0.f, 0.f, 0.f, 0.f};

        #pragma unroll
        for (int ks = 0; ks < 2; ks++) {
            bf16x8 wf[4];
            #pragma unroll
            for (int nt = 0; nt < 4; nt++)
                wf[nt] = *(const bf16x8*)(w1f + (((w * 4 + nt) * 2 + ks) << 9) + lane * 8);
            const int c = ks * 4 + q;
            #pragma unroll
            for (int mt = 0; mt < 4; mt++) {
                const int m = mt * 16 + lc;
                bf16x8 hf = *(const bf16x8*)(&Xls[m * 64 + ((c ^ (m & 7)) << 3)]);
                #pragma unroll
                for (int nt = 0; nt < 4; nt++)
                    acc[mt][nt] = __builtin_amdgcn_mfma_f32_16x16x32_bf16(wf[nt], hf, acc[mt][nt], 0, 0, 0);
            }
        }
        #pragma unroll
        for (int nt = 0; nt < 4; nt++) {
            const floatx4 bs = *(const floatx4*)(bp1 + w * 64 + nt * 16 + q * 4);
            const int chunk = w * 8 + nt * 2 + (q >> 1);
            #pragma unroll
            for (int mt = 0; mt < 4; mt++) {
                const int m = mt * 16 + lc;
                s4v hv;
                #pragma unroll
                for (int r = 0; r < 4; r++) {
                    float v = acc[mt][nt][r] + bs[r];
                    hv[r] = f2bf(v > 0.f ? v : 0.f);
                }
                *(s4v*)(&Hb[0][m * 256 + ((chunk ^ (m & 7)) << 3) + ((q & 1) << 2)]) = hv;
            }
        }
    }
    __syncthreads();

    // L2: H2'[n=256][m=64] = W2 x H1^T, relu
    {
        floatx4 acc[4][4];
        #pragma unroll
        for (int mt = 0; mt < 4; mt++)
            #pragma unroll
            for (int nt = 0; nt < 4; nt++)
                acc[mt][nt] = (floatx4){0.f, 0.f, 0.f, 0.f};

        #pragma unroll
        for (int ks = 0; ks < 8; ks++) {
            bf16x8 wf[4];
            #pragma unroll
            for (int nt = 0; nt < 4; nt++)
                wf[nt] = *(const bf16x8*)(w2f + (((w * 4 + nt) * 8 + ks) << 9) + lane * 8);
            const int c = ks * 4 + q;
            #pragma unroll
            for (int mt = 0; mt < 4; mt++) {
                const int m = mt * 16 + lc;
                bf16x8 hf = *(const bf16x8*)(&Hb[0][m * 256 + ((c ^ (m & 7)) << 3)]);
                #pragma unroll
                for (int nt = 0; nt < 4; nt++)
                    acc[mt][nt] = __builtin_amdgcn_mfma_f32_16x16x32_bf16(wf[nt], hf, acc[mt][nt], 0, 0, 0);
            }
        }
        #pragma unroll
        for (int nt = 0; nt < 4; nt++) {
            const floatx4 bs = *(const floatx4*)(bp2 + w * 64 + nt * 16 + q * 4);
            const int chunk = w * 8 + nt * 2 + (q >> 1);
            #pragma unroll
            for (int mt = 0; mt < 4; mt++) {
                const int m = mt * 16 + lc;
                s4v hv;
                #pragma unroll
                for (int r = 0; r < 4; r++) {
                    float v = acc[mt][nt][r] + bs[r];
                    hv[r] = f2bf(v > 0.f ? v : 0.f);
                }
                *(s4v*)(&Hb[1][m * 256 + ((chunk ^ (m & 7)) << 3) + ((q & 1) << 2)]) = hv;
            }
        }
    }
    __syncthreads();

    // L3: H3'[n=64][m=64] = W3 x H2^T (no relu) -> fp32 h3f[m][68]
    {
        floatx4 acc3[4];
        #pragma unroll
        for (int mt = 0; mt < 4; mt++) acc3[mt] = (floatx4){0.f, 0.f, 0.f, 0.f};

        #pragma unroll
        for (int ks = 0; ks < 8; ks++) {
            bf16x8 wf = *(const bf16x8*)(w3f + (((w * 8 + ks)) << 9) + lane * 8);
            const int c = ks * 4 + q;
            #pragma unroll
            for (int mt = 0; mt < 4; mt++) {
                const int m = mt * 16 + lc;
                bf16x8 hf = *(const bf16x8*)(&Hb[1][m * 256 + ((c ^ (m & 7)) << 3)]);
                acc3[mt] = __builtin_amdgcn_mfma_f32_16x16x32_bf16(wf, hf, acc3[mt], 0, 0, 0);
            }
        }
        const floatx4 bs = *(const floatx4*)(bp3 + w * 16 + q * 4);
        __syncthreads();   // all waves done reading Hb[0] region (L2) before h3f overlay write
        #pragma unroll
        for (int mt = 0; mt < 4; mt++) {
            const int m = mt * 16 + lc;
            floatx4 hv;
            #pragma unroll
            for (int r = 0; r < 4; r++) hv[r] = acc3[mt][r] + bs[r];
            *(floatx4*)(&h3f[m * 68 + w * 16 + q * 4]) = hv;
        }
    }
    __syncthreads();

    // L4: 64 -> 6 (scalar fp32, numerically identical to reference path)
    for (int e = tid; e < 384; e += 256) {
        int c = e >> 6, p = e & 63;
        float a = bp4[c];
        const float* wr = wp4 + c * 64;
        const float* xr = h3f + p * 68;
        #pragma unroll 8
        for (int k = 0; k < 64; k++) a += wr[k] * xr[k];
        out[(size_t)c * NPTS + pb + p] = a;
    }
}

extern "C" void kernel_launch(void* const* d_in, const int* in_sizes, int n_in,
                              void* d_out, int out_size, void* d_ws, size_t ws_size,
                              hipStream_t stream) {
    const float* img = (const float*)d_in[0];
    const int* c0 = (const int*)d_in[1];
    const int* c1 = (const int*)d_in[2];
    const int* c2 = (const int*)d_in[3];
    const float* w_enc1 = (const float*)d_in[4];
    const float* b_enc1 = (const float*)d_in[5];
    const float* w_enc2 = (const float*)d_in[6];
    const float* b_enc2 = (const float*)d_in[7];
    const float* w_p1 = (const float*)d_in[8];
    const float* b_p1 = (const float*)d_in[9];
    const float* w_p2 = (const float*)d_in[10];
    const float* b_p2 = (const float*)d_in[11];
    const float* w_p3 = (const float*)d_in[12];
    const float* b_p3 = (const float*)d_in[13];
    const float* w_p4 = (const float*)d_in[14];
    const float* b_p4 = (const float*)d_in[15];
    float* out = (float*)d_out;

    short* f1b = (short*)d_ws;                       // 32,768,000
    short* wpb = f1b + (size_t)VOX * 64;             // 110592 (conv2 B, fragment order)
    short* w1b = wpb + 110592;                       // 16384 (MLP L1 A-frags)
    short* w2b = w1b + 16384;                        // 65536 (MLP L2 A-frags)
    short* w3b = w2b + 65536;                        // 16384 (MLP L3 A-frags)
    short* gb  = w3b + 16384;                        // 12,800,000
    short* img_t = gb + (size_t)NPTS * 64;           // 16,384,000
    short* wc1 = img_t + (size_t)VOX * 32;           // 55296
    short* zeros = wc1 + 55296;                      // 64 shorts (128 B zero source)

    // sort arrays alias img_t (free after conv1 consumes it)
    int* perm      = (int*)img_t;                    // 200000
    int* pcoord    = perm + NPTS;                    // 200000
    int* partial   = pcoord + NPTS;                  // 32*1000  [cell][block]
    int* blockbase = partial + NSB * 1000;           // 32*1000  [cell][block]
    int* cstart    = blockbase + NSB * 1000;         // 1000
    int* cend      = cstart + 1000;                  // 1000

    hipMemsetAsync(zeros, 0, 128, stream);
    convert_weights<<<(264192 + 255) / 256, 256, 0, stream>>>(
        w_enc2, w_p1, w_p2, w_p3, w_enc1, wpb, w1b, w2b, w3b, wc1);
    transpose_img<<<(VOX + 255) / 256, 256, 0, stream>>>(img, img_t);
    conv1_mfma<<<DD * DD, 256, 0, stream>>>(img_t, wc1, b_enc1, zeros, f1b);

    // LDS-histogram counting sort into 8^3 cells
    hist_cells<<<NSB, 512, 0, stream>>>(c0, c1, c2, partial);
    scan_cells<<<1, 1024, 0, stream>>>(partial, blockbase, cstart, cend);
    scatter_points<<<NSB, 512, 0, stream>>>(c0, c1, c2, cstart, blockbase, perm, pcoord);

    conv2_halo<<<1000, 512, 0, stream>>>(
        f1b, wpb, b_enc2, cstart, cend, perm, pcoord, zeros, (__hip_bfloat16*)gb);
    mlp_mfma<<<NPTS / 64, 256, 0, stream>>>(
        (const __hip_bfloat16*)gb, w1b, b_p1, w2b, b_p2, w3b, b_p3, w_p4, b_p4, out);
}